// Round 4
// baseline (1694.795 us; speedup 1.0000x reference)
//
#include <hip/hip_runtime.h>
#include <hip/hip_bf16.h>

// Problem constants
#define Ecst 1024
#define Hh 16
#define Dd 64
#define Cc_ 64
#define Bb 4
#define Nn_ 4096
#define Mrows (Bb*Nn_)          // 16384 token rows
#define BNE (Bb*Nn_*Ecst)       // 16,777,216

typedef __attribute__((ext_vector_type(4))) float f32x4;
typedef __attribute__((ext_vector_type(8))) short short8;
typedef __attribute__((ext_vector_type(4))) unsigned short ushort4v;

__device__ __forceinline__ float bf2f(unsigned short u) {
    union { float f; unsigned int i; } x; x.i = ((unsigned int)u) << 16; return x.f;
}
__device__ __forceinline__ unsigned short f2bf(float f) {
    __hip_bfloat16 h = __float2bfloat16(f);
    return *reinterpret_cast<unsigned short*>(&h);
}
// async global->LDS, 16B per lane. lds ptr must be wave-uniform base (+lane*16 implicit).
__device__ __forceinline__ void glds16(const unsigned short* g, unsigned short* l) {
    __builtin_amdgcn_global_load_lds(
        (const __attribute__((address_space(1))) unsigned int*)g,
        (__attribute__((address_space(3))) unsigned int*)l, 16, 0, 0);
}

// ---------------- weight transpose + cast: in [R][C] f32 -> out [C][R] bf16 ----
__global__ __launch_bounds__(256) void transpose_cast(const float* __restrict__ in,
                                                      unsigned short* __restrict__ out,
                                                      int R, int Cc) {
    __shared__ float tile[32][33];
    int c0 = blockIdx.x * 32, r0 = blockIdx.y * 32;
    int tx = threadIdx.x, ty = threadIdx.y;      // block (32,8)
#pragma unroll
    for (int i = 0; i < 4; ++i)
        tile[ty + i*8][tx] = in[(size_t)(r0 + ty + i*8) * Cc + c0 + tx];
    __syncthreads();
#pragma unroll
    for (int i = 0; i < 4; ++i)
        out[(size_t)(c0 + ty + i*8) * R + r0 + tx] = f2bf(tile[tx][ty + i*8]);
}

__global__ __launch_bounds__(256) void concat3(const float* __restrict__ a,
                                               const float* __restrict__ b,
                                               const float* __restrict__ c,
                                               float* __restrict__ o) {
    int i = blockIdx.x * 256 + threadIdx.x;
    if (i < 1024) { o[i] = a[i]; o[1024 + i] = b[i]; o[2048 + i] = c[i]; }
}

// ---------------- LayerNorm: x f32 [rows][1024] -> out bf16 -------------------
__global__ __launch_bounds__(256) void ln_kernel(const float* __restrict__ x,
                                                 const float* __restrict__ g,
                                                 const float* __restrict__ be,
                                                 unsigned short* __restrict__ out) {
    int row = blockIdx.x, tid = threadIdx.x;
    const float4 xv = *(const float4*)(x + (size_t)row * Ecst + tid * 4);
    float s = xv.x + xv.y + xv.z + xv.w;
    float q = xv.x*xv.x + xv.y*xv.y + xv.z*xv.z + xv.w*xv.w;
#pragma unroll
    for (int off = 32; off; off >>= 1) { s += __shfl_xor(s, off); q += __shfl_xor(q, off); }
    __shared__ float sb[8];
    int lane = tid & 63, w = tid >> 6;
    if (lane == 0) { sb[w] = s; sb[4 + w] = q; }
    __syncthreads();
    s = sb[0] + sb[1] + sb[2] + sb[3];
    q = sb[4] + sb[5] + sb[6] + sb[7];
    float mean = s * (1.0f / Ecst);
    float var  = q * (1.0f / Ecst) - mean * mean;
    float rs = rsqrtf(var + 1e-5f);
    ushort4v o;
    const float* xp = (const float*)&xv;
#pragma unroll
    for (int u = 0; u < 4; ++u) {
        float val = (xp[u] - mean) * rs * g[tid*4+u] + be[tid*4+u];
        o[u] = f2bf(val);
    }
    *(ushort4v*)(out + (size_t)row * Ecst + tid * 4) = o;
}

// ---------------- bf16 MFMA GEMM: 256x256 tile, BK=32, 3-slot LDS ring --------
// T3+T4: compute tile t from slot t%3, stage tile t+2 into slot (t+2)%3 (dead
// since tile t-1); boundary = counted s_waitcnt vmcnt(4) + raw s_barrier (never
// a vmcnt(0) drain in steady state). T2: seg ^= (row>>1)&3 swizzle on BOTH the
// global_load_lds source and the ds_read offsets (rule #21) -> conflict-free
// (round-3 PMC: SQ_LDS_BANK_CONFLICT == 0). T1: XCD swizzle. T5: setprio.
// Round-4 fix: __launch_bounds__(512, 1). (512,2) was interpreted as a 128-VGPR
// cap -> acc[8][4] spilled to scratch (882 MB WRITE_SIZE, MfmaUtil 9%).
// EPI 0: Ob = bf16(acc+bias)
// EPI 1: Of = resid + acc + bias                  (x1 = x + attn_proj)
// EPI 2: Ob = bf16(gelu_exact(acc+bias))
// EPI 3: v = resid + acc + bias; Of = v; Of2 = v  (x2, written twice)
template<int EPI, int K>
__global__ __launch_bounds__(512, 1) void gemm256(const unsigned short* __restrict__ A,
                                                  const unsigned short* __restrict__ Bt,
                                                  const float* __restrict__ bias,
                                                  int Nc, int nbn,
                                                  unsigned short* __restrict__ Ob,
                                                  float* __restrict__ Of,
                                                  const float* __restrict__ resid,
                                                  float* __restrict__ Of2) {
    extern __shared__ unsigned short smem[];
    unsigned short* const As0 = smem;
    unsigned short* const As1 = smem + 8192;
    unsigned short* const As2 = smem + 16384;
    unsigned short* const Bs0 = smem + 24576;
    unsigned short* const Bs1 = smem + 32768;
    unsigned short* const Bs2 = smem + 40960;
    constexpr int NT = K / 32;
    const int tid = threadIdx.x;
    const int lane = tid & 63, wid = tid >> 6;
    const int wm = wid >> 2, wn = wid & 3;        // wave tile: 128 rows x 64 cols
    const int l = lane & 15, g = lane >> 4;
    // XCD-aware swizzle (all grids divisible by 8)
    const int nwg = gridDim.x, cpx = nwg >> 3;
    const int orig = blockIdx.x;
    const int wg = (orig & 7) * cpx + (orig >> 3);
    const int tm = (wg / nbn) * 256, tn = (wg % nbn) * 256;
    // staging precompute: 2 sweeps x (A,B) = 4 glds/tile; 16B unit c -> row c>>2, seg c&3
    const int c0 = tid, c1 = 512 + tid;
    const int r0 = c0 >> 2, r1 = c1 >> 2;
    const int sg0 = (c0 & 3) ^ ((r0 >> 1) & 3);
    const int sg1 = (c1 & 3) ^ ((r1 >> 1) & 3);
    const size_t aO0 = (size_t)(tm + r0) * K + sg0 * 8;
    const size_t aO1 = (size_t)(tm + r1) * K + sg1 * 8;
    const size_t bO0 = (size_t)(tn + r0) * K + sg0 * 8;
    const size_t bO1 = (size_t)(tn + r1) * K + sg1 * 8;
    const int wls0 = wid * 512;          // LDS elem base, sweep 0 (wave-uniform)
    const int wls1 = 4096 + wid * 512;   // sweep 1
    auto stage = [&](int kt, unsigned short* SA, unsigned short* SB) {
        const unsigned short* gA = A + (size_t)kt * 32;
        const unsigned short* gB = Bt + (size_t)kt * 32;
        glds16(gA + aO0, SA + wls0);
        glds16(gB + bO0, SB + wls0);
        glds16(gA + aO1, SA + wls1);
        glds16(gB + bO1, SB + wls1);
    };
    // frag read offsets (seg swizzled with same involution as staging)
    const int seg = (g ^ ((l >> 1) & 3)) * 8;
    int frA[8], frB[4];
#pragma unroll
    for (int mi = 0; mi < 8; ++mi) frA[mi] = (wm * 128 + mi * 16 + l) * 32 + seg;
#pragma unroll
    for (int ni = 0; ni < 4; ++ni) frB[ni] = (wn * 64 + ni * 16 + l) * 32 + seg;

    f32x4 acc[8][4] = {};
    stage(0, As0, Bs0);
    stage(1, As1, Bs1);
    asm volatile("s_waitcnt vmcnt(4)" ::: "memory");   // tile 0 landed, tile 1 in flight
    __builtin_amdgcn_s_barrier();
    __builtin_amdgcn_sched_barrier(0);

#define TILEBODY(RA, RB, SA, SB) \
    { \
        if (t + 2 < NT) stage(t + 2, SA, SB); \
        short8 af[8], bfr[4]; \
        _Pragma("unroll") for (int mi = 0; mi < 8; ++mi) af[mi] = *(const short8*)(RA + frA[mi]); \
        _Pragma("unroll") for (int ni = 0; ni < 4; ++ni) bfr[ni] = *(const short8*)(RB + frB[ni]); \
        __builtin_amdgcn_s_setprio(1); \
        _Pragma("unroll") for (int mi = 0; mi < 8; ++mi) \
        _Pragma("unroll") for (int ni = 0; ni < 4; ++ni) \
            acc[mi][ni] = __builtin_amdgcn_mfma_f32_16x16x32_bf16(af[mi], bfr[ni], acc[mi][ni], 0, 0, 0); \
        __builtin_amdgcn_s_setprio(0); \
        if (t + 2 < NT) { asm volatile("s_waitcnt vmcnt(4)" ::: "memory"); } \
        else            { asm volatile("s_waitcnt vmcnt(0)" ::: "memory"); } \
        __builtin_amdgcn_s_barrier(); \
        __builtin_amdgcn_sched_barrier(0); \
    }

    int m3 = 0;
    for (int t = 0; t < NT; ++t) {
        if (m3 == 0)      TILEBODY(As0, Bs0, As2, Bs2)
        else if (m3 == 1) TILEBODY(As1, Bs1, As0, Bs0)
        else              TILEBODY(As2, Bs2, As1, Bs1)
        if (++m3 == 3) m3 = 0;
    }
#undef TILEBODY

    const int col = l, rquad = g * 4;
#pragma unroll
    for (int mi = 0; mi < 8; ++mi) {
#pragma unroll
        for (int ni = 0; ni < 4; ++ni) {
            int gcol = tn + wn * 64 + ni * 16 + col;
            float bia = bias[gcol];
#pragma unroll
            for (int j = 0; j < 4; ++j) {
                int grow = tm + wm * 128 + mi * 16 + rquad + j;
                size_t idx = (size_t)grow * Nc + gcol;
                float val = acc[mi][ni][j] + bia;
                if (EPI == 0) {
                    Ob[idx] = f2bf(val);
                } else if (EPI == 1) {
                    Of[idx] = resid[idx] + val;
                } else if (EPI == 2) {
                    Ob[idx] = f2bf(0.5f * val * (1.0f + erff(val * 0.70710678118654752f)));
                } else {
                    float v2 = resid[idx] + val;
                    Of[idx] = v2; Of2[idx] = v2;
                }
            }
        }
    }
}

// ---------------- chunked sliding-window attention (MFMA) ---------------------
// qkv fused layout [B*N][3072]: q at col h*64, k at 1024+h*64, v at 2048+h*64.
// One block per (b,h,chunk). Window slots [0,64) = prev chunk (zeros for chunk 0,
// UNMASKED per reference zero-pad); [64,128) = current chunk, masked col-64 <= row.
#define QS_OFF(r,d0) ((r)*64  + ((((d0)>>3) ^ ((r)&7))  << 3))
#define KS_OFF(j,d0) ((j)*64  + ((((d0)>>3) ^ ((j)&7))  << 3))
#define VT_OFF(d,j0) ((d)*128 + ((((j0)>>3) ^ ((d)&15)) << 3))
#define PS_OFF(r,c0) ((r)*128 + ((((c0)>>3) ^ ((r)&15)) << 3))
__global__ __launch_bounds__(256) void attn_mfma(const unsigned short* __restrict__ qkv,
                                                 unsigned short* __restrict__ ao) {
    __shared__ unsigned short qs[64 * 64];
    __shared__ unsigned short ks[128 * 64];
    __shared__ unsigned short vT[64 * 128];
    __shared__ unsigned short ps[64 * 128];
    int bx = blockIdx.x;
    int c = bx & 63, h = (bx >> 6) & 15, b = bx >> 10;
    int tid = threadIdx.x, lane = tid & 63, w = tid >> 6;
    const int QKV = 3 * Ecst;
    size_t baseq = ((size_t)b * Nn_ + c * 64) * QKV + h * 64;
    size_t baseo = ((size_t)b * Nn_ + c * 64) * Ecst + h * 64;
    // stage Q
#pragma unroll
    for (int i = 0; i < 2; ++i) {
        int cc = tid + i * 256;
        int row = cc >> 3, d0 = (cc & 7) * 8;
        short8 vq = *(const short8*)(qkv + baseq + (size_t)row * QKV + d0);
        *(short8*)(qs + QS_OFF(row, d0)) = vq;
    }
    // stage K row-major + V transposed
#pragma unroll
    for (int i = 0; i < 4; ++i) {
        int cc = tid + i * 256;
        int j = cc >> 3, d0 = (cc & 7) * 8;
        short8 vk = {}; short8 vv = {};
        if (c > 0 || j >= 64) {
            int srcRow = (j < 64) ? (c - 1) * 64 + j : c * 64 + (j - 64);
            size_t sb = ((size_t)b * Nn_ + srcRow) * QKV + h * 64 + d0;
            vk = *(const short8*)(qkv + sb + 1024);
            vv = *(const short8*)(qkv + sb + 2048);
        }
        *(short8*)(ks + KS_OFF(j, d0)) = vk;
#pragma unroll
        for (int u = 0; u < 8; ++u)
            vT[VT_OFF(d0 + u, j & ~7) + (j & 7)] = ((unsigned short*)&vv)[u];
    }
    __syncthreads();
    // QK^T: per wave M=16 (rows w*16..+16), N=128, K=64 -> 16 MFMAs
    const int rA = w * 16 + (lane & 15);
    const int ksel = (lane >> 4) * 8;
    f32x4 s[8] = {};
#pragma unroll
    for (int kk = 0; kk < 2; ++kk) {
        short8 aq = *(const short8*)(qs + QS_OFF(rA, kk * 32 + ksel));
#pragma unroll
        for (int ni = 0; ni < 8; ++ni) {
            int j = ni * 16 + (lane & 15);
            short8 bk = *(const short8*)(ks + KS_OFF(j, kk * 32 + ksel));
            s[ni] = __builtin_amdgcn_mfma_f32_16x16x32_bf16(aq, bk, s[ni], 0, 0, 0);
        }
    }
    // row softmax over 16-lane groups
    float inv[4];
    const int rq = (lane >> 4) * 4;
#pragma unroll
    for (int jr = 0; jr < 4; ++jr) {
        int i = w * 16 + rq + jr;
        float vals[8]; float mx = -1e30f;
#pragma unroll
        for (int ni = 0; ni < 8; ++ni) {
            int colw = ni * 16 + (lane & 15);
            bool valid = (colw < 64) || (colw - 64 <= i);
            float vv = valid ? s[ni][jr] * 0.125f : -1e30f;
            vals[ni] = vv;
            mx = fmaxf(mx, vv);
        }
#pragma unroll
        for (int off = 8; off; off >>= 1) mx = fmaxf(mx, __shfl_xor(mx, off));
        float sum = 0.f;
#pragma unroll
        for (int ni = 0; ni < 8; ++ni) {
            float e = (vals[ni] > -1e29f) ? __expf(vals[ni] - mx) : 0.f;
            vals[ni] = e; sum += e;
        }
#pragma unroll
        for (int off = 8; off; off >>= 1) sum += __shfl_xor(sum, off);
        inv[jr] = 1.0f / sum;
        int r = w * 16 + rq + jr;
#pragma unroll
        for (int ni = 0; ni < 8; ++ni) {
            int colw = ni * 16 + (lane & 15);
            ps[PS_OFF(r, colw & ~7) + (colw & 7)] = f2bf(vals[ni]);
        }
    }
    __syncthreads();
    // PV: per wave M=16, N=64, K=128 -> 16 MFMAs
    f32x4 o[4] = {};
#pragma unroll
    for (int kk = 0; kk < 4; ++kk) {
        short8 ap = *(const short8*)(ps + PS_OFF(rA, kk * 32 + ksel));
#pragma unroll
        for (int ni = 0; ni < 4; ++ni) {
            int d = ni * 16 + (lane & 15);
            short8 bv = *(const short8*)(vT + VT_OFF(d, kk * 32 + ksel));
            o[ni] = __builtin_amdgcn_mfma_f32_16x16x32_bf16(ap, bv, o[ni], 0, 0, 0);
        }
    }
#pragma unroll
    for (int ni = 0; ni < 4; ++ni) {
#pragma unroll
        for (int jr = 0; jr < 4; ++jr) {
            int row = w * 16 + rq + jr;
            int d = ni * 16 + (lane & 15);
            ao[baseo + (size_t)row * Ecst + d] = f2bf(o[ni][jr] * inv[jr]);
        }
    }
}

// ---------------- loss ---------------------------------------------------------
__global__ __launch_bounds__(256) void loss_partial(const float* __restrict__ x2,
                                                    const float* __restrict__ p,
                                                    float* __restrict__ partials) {
    float s = 0.f;
    for (size_t idx = (size_t)blockIdx.x * 256 + threadIdx.x; idx < BNE / 4; idx += (size_t)gridDim.x * 256) {
        float4 a = *(const float4*)(x2 + idx * 4);
        float4 b = *(const float4*)(p + idx * 4);
        float dx = a.x - b.x, dy = a.y - b.y, dz = a.z - b.z, dw = a.w - b.w;
        s += dx*dx + dy*dy + dz*dz + dw*dw;
    }
#pragma unroll
    for (int off = 32; off; off >>= 1) s += __shfl_xor(s, off);
    __shared__ float sb[4];
    int lane = threadIdx.x & 63, w = threadIdx.x >> 6;
    if (lane == 0) sb[w] = s;
    __syncthreads();
    if (threadIdx.x == 0) partials[blockIdx.x] = sb[0] + sb[1] + sb[2] + sb[3];
}

__global__ __launch_bounds__(256) void loss_final(const float* __restrict__ partials,
                                                  float* __restrict__ out) {
    float s = 0.f;
    for (int i = threadIdx.x; i < 2048; i += 256) s += partials[i];
#pragma unroll
    for (int off = 32; off; off >>= 1) s += __shfl_xor(s, off);
    __shared__ float sb[4];
    int lane = threadIdx.x & 63, w = threadIdx.x >> 6;
    if (lane == 0) sb[w] = s;
    __syncthreads();
    if (threadIdx.x == 0) out[0] = (sb[0] + sb[1] + sb[2] + sb[3]) * (1.0f / (float)BNE);
}

extern "C" void kernel_launch(void* const* d_in, const int* in_sizes, int n_in,
                              void* d_out, int out_size, void* d_ws, size_t ws_size,
                              hipStream_t stream) {
    const float* x     = (const float*)d_in[0];
    const float* p     = (const float*)d_in[1];
    const float* wq    = (const float*)d_in[2];
    const float* bq    = (const float*)d_in[3];
    const float* wk    = (const float*)d_in[4];
    const float* bk    = (const float*)d_in[5];
    const float* wv    = (const float*)d_in[6];
    const float* bv    = (const float*)d_in[7];
    const float* wo    = (const float*)d_in[8];
    const float* bo    = (const float*)d_in[9];
    const float* w1    = (const float*)d_in[10];
    const float* b1    = (const float*)d_in[11];
    const float* w2    = (const float*)d_in[12];
    const float* b2    = (const float*)d_in[13];
    const float* g1    = (const float*)d_in[14];
    const float* beta1 = (const float*)d_in[15];
    const float* g2    = (const float*)d_in[16];
    const float* beta2 = (const float*)d_in[17];

    char* ws = (char*)d_ws;
    size_t off = 0;
    auto alloc = [&](size_t bytes) { void* pp = ws + off; off += (bytes + 255) & ~(size_t)255; return pp; };
    unsigned short* wqkvT = (unsigned short*)alloc((size_t)3 * Ecst * Ecst * 2);
    unsigned short* woT  = (unsigned short*)alloc((size_t)Ecst * Ecst * 2);
    unsigned short* w1T  = (unsigned short*)alloc((size_t)4 * Ecst * Ecst * 2);
    unsigned short* w2T  = (unsigned short*)alloc((size_t)4 * Ecst * Ecst * 2);
    float* bqkv          = (float*)alloc(3 * Ecst * 4);
    unsigned short* xn   = (unsigned short*)alloc((size_t)Mrows * Ecst * 2);  // reused as h after LN2
    unsigned short* qkv  = (unsigned short*)alloc((size_t)Mrows * 3 * Ecst * 2);
    unsigned short* aob  = (unsigned short*)alloc((size_t)Mrows * Ecst * 2);
    unsigned short* ff1  = (unsigned short*)alloc((size_t)Mrows * 4 * Ecst * 2);
    float* partials      = (float*)alloc(2048 * 4);

    float* x1 = (float*)d_out;                    // [0, BNE): x1 then x2 (copy 0)
    float* out2 = (float*)d_out + BNE;            // x2 (copy 1)
    float* lossp = (float*)d_out + 2 * (size_t)BNE;

    const int SMEM = 96 * 1024;
    hipFuncSetAttribute((const void*)gemm256<0, 1024>, hipFuncAttributeMaxDynamicSharedMemorySize, SMEM);
    hipFuncSetAttribute((const void*)gemm256<1, 1024>, hipFuncAttributeMaxDynamicSharedMemorySize, SMEM);
    hipFuncSetAttribute((const void*)gemm256<2, 1024>, hipFuncAttributeMaxDynamicSharedMemorySize, SMEM);
    hipFuncSetAttribute((const void*)gemm256<3, 4096>, hipFuncAttributeMaxDynamicSharedMemorySize, SMEM);

    dim3 tb(32, 8);
    transpose_cast<<<dim3(32, 32),  tb, 0, stream>>>(wq, wqkvT, Ecst, Ecst);
    transpose_cast<<<dim3(32, 32),  tb, 0, stream>>>(wk, wqkvT + (size_t)Ecst * Ecst, Ecst, Ecst);
    transpose_cast<<<dim3(32, 32),  tb, 0, stream>>>(wv, wqkvT + (size_t)2 * Ecst * Ecst, Ecst, Ecst);
    transpose_cast<<<dim3(32, 32),  tb, 0, stream>>>(wo, woT, Ecst, Ecst);
    transpose_cast<<<dim3(128, 32), tb, 0, stream>>>(w1, w1T, Ecst, 4 * Ecst);
    transpose_cast<<<dim3(32, 128), tb, 0, stream>>>(w2, w2T, 4 * Ecst, Ecst);
    concat3<<<4, 256, 0, stream>>>(bq, bk, bv, bqkv);

    ln_kernel<<<Mrows, 256, 0, stream>>>(x, g1, beta1, xn);

    // fused QKV: M=16384, N=3072, K=1024
    gemm256<0, 1024><<<64 * 12, 512, SMEM, stream>>>(xn, wqkvT, bqkv, 3 * Ecst, 12, qkv, nullptr, nullptr, nullptr);

    attn_mfma<<<Bb * Hh * (Nn_ / Cc_), 256, 0, stream>>>(qkv, aob);

    gemm256<1, 1024><<<64 * 4, 512, SMEM, stream>>>(aob, woT, bo, Ecst, 4, nullptr, x1, x, nullptr);

    ln_kernel<<<Mrows, 256, 0, stream>>>(x1, g2, beta2, xn);

    gemm256<2, 1024><<<64 * 16, 512, SMEM, stream>>>(xn, w1T, b1, 4 * Ecst, 16, ff1, nullptr, nullptr, nullptr);

    gemm256<3, 4096><<<64 * 4, 512, SMEM, stream>>>(ff1, w2T, b2, Ecst, 4, nullptr, x1, x1, out2);

    loss_partial<<<2048, 256, 0, stream>>>((const float*)d_out, p, partials);
    loss_final<<<1, 256, 0, stream>>>(partials, lossp);
}

// Round 5
// 1338.736 us; speedup vs baseline: 1.2660x; 1.2660x over previous
//
#include <hip/hip_runtime.h>
#include <hip/hip_bf16.h>

// Problem constants
#define Ecst 1024
#define Hh 16
#define Dd 64
#define Cc_ 64
#define Bb 4
#define Nn_ 4096
#define Mrows (Bb*Nn_)          // 16384 token rows
#define BNE (Bb*Nn_*Ecst)       // 16,777,216

typedef __attribute__((ext_vector_type(4))) float f32x4;
typedef __attribute__((ext_vector_type(8))) short short8;
typedef __attribute__((ext_vector_type(4))) unsigned short ushort4v;

__device__ __forceinline__ float bf2f(unsigned short u) {
    union { float f; unsigned int i; } x; x.i = ((unsigned int)u) << 16; return x.f;
}
__device__ __forceinline__ unsigned short f2bf(float f) {
    __hip_bfloat16 h = __float2bfloat16(f);
    return *reinterpret_cast<unsigned short*>(&h);
}
// async global->LDS, 16B per lane. lds ptr must be wave-uniform base (+lane*16 implicit).
__device__ __forceinline__ void glds16(const unsigned short* g, unsigned short* l) {
    __builtin_amdgcn_global_load_lds(
        (const __attribute__((address_space(1))) unsigned int*)g,
        (__attribute__((address_space(3))) unsigned int*)l, 16, 0, 0);
}

// ---------------- weight transpose + cast: in [R][C] f32 -> out [C][R] bf16 ----
__global__ __launch_bounds__(256) void transpose_cast(const float* __restrict__ in,
                                                      unsigned short* __restrict__ out,
                                                      int R, int Cc) {
    __shared__ float tile[32][33];
    int c0 = blockIdx.x * 32, r0 = blockIdx.y * 32;
    int tx = threadIdx.x, ty = threadIdx.y;      // block (32,8)
#pragma unroll
    for (int i = 0; i < 4; ++i)
        tile[ty + i*8][tx] = in[(size_t)(r0 + ty + i*8) * Cc + c0 + tx];
    __syncthreads();
#pragma unroll
    for (int i = 0; i < 4; ++i)
        out[(size_t)(c0 + ty + i*8) * R + r0 + tx] = f2bf(tile[tx][ty + i*8]);
}

__global__ __launch_bounds__(256) void concat3(const float* __restrict__ a,
                                               const float* __restrict__ b,
                                               const float* __restrict__ c,
                                               float* __restrict__ o) {
    int i = blockIdx.x * 256 + threadIdx.x;
    if (i < 1024) { o[i] = a[i]; o[1024 + i] = b[i]; o[2048 + i] = c[i]; }
}

// ---------------- LayerNorm: x f32 [rows][1024] -> out bf16 -------------------
__global__ __launch_bounds__(256) void ln_kernel(const float* __restrict__ x,
                                                 const float* __restrict__ g,
                                                 const float* __restrict__ be,
                                                 unsigned short* __restrict__ out) {
    int row = blockIdx.x, tid = threadIdx.x;
    const float4 xv = *(const float4*)(x + (size_t)row * Ecst + tid * 4);
    float s = xv.x + xv.y + xv.z + xv.w;
    float q = xv.x*xv.x + xv.y*xv.y + xv.z*xv.z + xv.w*xv.w;
#pragma unroll
    for (int off = 32; off; off >>= 1) { s += __shfl_xor(s, off); q += __shfl_xor(q, off); }
    __shared__ float sb[8];
    int lane = tid & 63, w = tid >> 6;
    if (lane == 0) { sb[w] = s; sb[4 + w] = q; }
    __syncthreads();
    s = sb[0] + sb[1] + sb[2] + sb[3];
    q = sb[4] + sb[5] + sb[6] + sb[7];
    float mean = s * (1.0f / Ecst);
    float var  = q * (1.0f / Ecst) - mean * mean;
    float rs = rsqrtf(var + 1e-5f);
    ushort4v o;
    const float* xp = (const float*)&xv;
#pragma unroll
    for (int u = 0; u < 4; ++u) {
        float val = (xp[u] - mean) * rs * g[tid*4+u] + be[tid*4+u];
        o[u] = f2bf(val);
    }
    *(ushort4v*)(out + (size_t)row * Ecst + tid * 4) = o;
}

// Common epilogue
#define EPILOGUE(grow_expr, gcol_expr, MREP, NREP) \
    { \
        _Pragma("unroll") for (int mi = 0; mi < MREP; ++mi) { \
        _Pragma("unroll") for (int ni = 0; ni < NREP; ++ni) { \
            int gcol = gcol_expr; \
            float bia = bias[gcol]; \
            _Pragma("unroll") for (int j = 0; j < 4; ++j) { \
                int grow = grow_expr; \
                size_t idx = (size_t)grow * Nc + gcol; \
                float val = acc[mi][ni][j] + bia; \
                if (EPI == 0) { \
                    Ob[idx] = f2bf(val); \
                } else if (EPI == 1) { \
                    Of[idx] = resid[idx] + val; \
                } else if (EPI == 2) { \
                    Ob[idx] = f2bf(0.5f * val * (1.0f + erff(val * 0.70710678118654752f))); \
                } else { \
                    float v2 = resid[idx] + val; \
                    Of[idx] = v2; Of2[idx] = v2; \
                } \
            } \
        } } \
    }

// ---------------- bf16 MFMA GEMM A: 256x256 tile, BK=32, 3-slot LDS ring ------
// Proven conflict-free (round-3 PMC: SQ_LDS_BANK_CONFLICT == 0) but spilled at
// the allocator's default 128-VGPR budget (launch_bounds 2nd arg had NO effect,
// rounds 3-4 identical). Round-5 fix: explicit amdgpu_waves_per_eu(2,2)
// (budget = 512/2 = 256 VGPR; 96KB LDS caps us at 2 waves/EU anyway) and
// interleaved A-frag loads (af liveness 32 -> 8 VGPRs).
template<int EPI, int K>
__global__ __launch_bounds__(512) __attribute__((amdgpu_waves_per_eu(2, 2)))
void gemm256(const unsigned short* __restrict__ A,
             const unsigned short* __restrict__ Bt,
             const float* __restrict__ bias,
             int Nc, int nbn,
             unsigned short* __restrict__ Ob,
             float* __restrict__ Of,
             const float* __restrict__ resid,
             float* __restrict__ Of2) {
    extern __shared__ unsigned short smem[];
    unsigned short* const As0 = smem;
    unsigned short* const As1 = smem + 8192;
    unsigned short* const As2 = smem + 16384;
    unsigned short* const Bs0 = smem + 24576;
    unsigned short* const Bs1 = smem + 32768;
    unsigned short* const Bs2 = smem + 40960;
    constexpr int NT = K / 32;
    const int tid = threadIdx.x;
    const int lane = tid & 63, wid = tid >> 6;
    const int wm = wid >> 2, wn = wid & 3;        // wave tile: 128 rows x 64 cols
    const int l = lane & 15, g = lane >> 4;
    const int nwg = gridDim.x, cpx = nwg >> 3;
    const int orig = blockIdx.x;
    const int wg = (orig & 7) * cpx + (orig >> 3);
    const int tm = (wg / nbn) * 256, tn = (wg % nbn) * 256;
    const int c0 = tid, c1 = 512 + tid;
    const int r0 = c0 >> 2, r1 = c1 >> 2;
    const int sg0 = (c0 & 3) ^ ((r0 >> 1) & 3);
    const int sg1 = (c1 & 3) ^ ((r1 >> 1) & 3);
    const size_t aO0 = (size_t)(tm + r0) * K + sg0 * 8;
    const size_t aO1 = (size_t)(tm + r1) * K + sg1 * 8;
    const size_t bO0 = (size_t)(tn + r0) * K + sg0 * 8;
    const size_t bO1 = (size_t)(tn + r1) * K + sg1 * 8;
    const int wls0 = wid * 512;
    const int wls1 = 4096 + wid * 512;
    auto stage = [&](int kt, unsigned short* SA, unsigned short* SB) {
        const unsigned short* gA = A + (size_t)kt * 32;
        const unsigned short* gB = Bt + (size_t)kt * 32;
        glds16(gA + aO0, SA + wls0);
        glds16(gB + bO0, SB + wls0);
        glds16(gA + aO1, SA + wls1);
        glds16(gB + bO1, SB + wls1);
    };
    const int seg = (g ^ ((l >> 1) & 3)) * 8;
    int frA[8], frB[4];
#pragma unroll
    for (int mi = 0; mi < 8; ++mi) frA[mi] = (wm * 128 + mi * 16 + l) * 32 + seg;
#pragma unroll
    for (int ni = 0; ni < 4; ++ni) frB[ni] = (wn * 64 + ni * 16 + l) * 32 + seg;

    f32x4 acc[8][4] = {};
    stage(0, As0, Bs0);
    stage(1, As1, Bs1);
    asm volatile("s_waitcnt vmcnt(4)" ::: "memory");
    __builtin_amdgcn_s_barrier();
    __builtin_amdgcn_sched_barrier(0);

#define TILEBODY6(RA, RB, SA, SB) \
    { \
        if (t + 2 < NT) stage(t + 2, SA, SB); \
        short8 bfr[4]; \
        _Pragma("unroll") for (int ni = 0; ni < 4; ++ni) bfr[ni] = *(const short8*)(RB + frB[ni]); \
        __builtin_amdgcn_s_setprio(1); \
        _Pragma("unroll") for (int mi = 0; mi < 8; ++mi) { \
            short8 af = *(const short8*)(RA + frA[mi]); \
            _Pragma("unroll") for (int ni = 0; ni < 4; ++ni) \
                acc[mi][ni] = __builtin_amdgcn_mfma_f32_16x16x32_bf16(af, bfr[ni], acc[mi][ni], 0, 0, 0); \
        } \
        __builtin_amdgcn_s_setprio(0); \
        if (t + 2 < NT) { asm volatile("s_waitcnt vmcnt(4)" ::: "memory"); } \
        else            { asm volatile("s_waitcnt vmcnt(0)" ::: "memory"); } \
        __builtin_amdgcn_s_barrier(); \
        __builtin_amdgcn_sched_barrier(0); \
    }

    int m3 = 0;
    for (int t = 0; t < NT; ++t) {
        if (m3 == 0)      TILEBODY6(As0, Bs0, As2, Bs2)
        else if (m3 == 1) TILEBODY6(As1, Bs1, As0, Bs0)
        else              TILEBODY6(As2, Bs2, As1, Bs1)
        if (++m3 == 3) m3 = 0;
    }
#undef TILEBODY6

    EPILOGUE(tm + wm * 128 + mi * 16 + g * 4 + j, tn + wn * 64 + ni * 16 + l, 8, 4)
}

// ---------------- bf16 MFMA GEMM B: 256x128 tile, BK=32, 3-slot LDS ring ------
// Low-pressure hedge: 8 waves x 64x64 wave tile -> acc[4][4] = 64 VGPRs; fits
// a 128-VGPR budget without spill. 72KB LDS -> 2 blocks/CU possible.
template<int EPI, int K>
__global__ __launch_bounds__(512)
void gemm128w(const unsigned short* __restrict__ A,
              const unsigned short* __restrict__ Bt,
              const float* __restrict__ bias,
              int Nc, int nbn,
              unsigned short* __restrict__ Ob,
              float* __restrict__ Of,
              const float* __restrict__ resid,
              float* __restrict__ Of2) {
    extern __shared__ unsigned short smem[];
    unsigned short* const As0 = smem;             // 3 x 8192 elems
    unsigned short* const As1 = smem + 8192;
    unsigned short* const As2 = smem + 16384;
    unsigned short* const Bs0 = smem + 24576;     // 3 x 4096 elems
    unsigned short* const Bs1 = smem + 28672;
    unsigned short* const Bs2 = smem + 32768;
    constexpr int NT = K / 32;
    const int tid = threadIdx.x;
    const int lane = tid & 63, wid = tid >> 6;
    const int wm = wid >> 1, wn = wid & 1;        // wave tile: 64 rows x 64 cols
    const int l = lane & 15, g = lane >> 4;
    const int nwg = gridDim.x, cpx = nwg >> 3;
    const int orig = blockIdx.x;
    const int wg = (orig & 7) * cpx + (orig >> 3);
    const int tm = (wg / nbn) * 256, tn = (wg % nbn) * 128;
    // A: 1024 16B-units (2 sweeps), B: 512 units (1 sweep)
    const int uA0 = tid, uA1 = 512 + tid, uB = tid;
    const int rA0 = uA0 >> 2, rA1 = uA1 >> 2, rB = uB >> 2;
    const int sgA0 = (uA0 & 3) ^ ((rA0 >> 1) & 3);
    const int sgA1 = (uA1 & 3) ^ ((rA1 >> 1) & 3);
    const int sgB  = (uB  & 3) ^ ((rB  >> 1) & 3);
    const size_t aO0 = (size_t)(tm + rA0) * K + sgA0 * 8;
    const size_t aO1 = (size_t)(tm + rA1) * K + sgA1 * 8;
    const size_t bO0 = (size_t)(tn + rB ) * K + sgB  * 8;
    const int wlsA0 = wid * 512, wlsA1 = 4096 + wid * 512, wlsB = wid * 512;
    auto stage = [&](int kt, unsigned short* SA, unsigned short* SB) {
        const unsigned short* gA = A + (size_t)kt * 32;
        const unsigned short* gB = Bt + (size_t)kt * 32;
        glds16(gA + aO0, SA + wlsA0);
        glds16(gA + aO1, SA + wlsA1);
        glds16(gB + bO0, SB + wlsB);
    };
    const int seg = (g ^ ((l >> 1) & 3)) * 8;
    int frA[4], frB[4];
#pragma unroll
    for (int mi = 0; mi < 4; ++mi) frA[mi] = (wm * 64 + mi * 16 + l) * 32 + seg;
#pragma unroll
    for (int ni = 0; ni < 4; ++ni) frB[ni] = (wn * 64 + ni * 16 + l) * 32 + seg;

    f32x4 acc[4][4] = {};
    stage(0, As0, Bs0);
    stage(1, As1, Bs1);
    asm volatile("s_waitcnt vmcnt(3)" ::: "memory");
    __builtin_amdgcn_s_barrier();
    __builtin_amdgcn_sched_barrier(0);

#define TILEBODY3(RA, RB, SA, SB) \
    { \
        if (t + 2 < NT) stage(t + 2, SA, SB); \
        short8 bfr[4]; \
        _Pragma("unroll") for (int ni = 0; ni < 4; ++ni) bfr[ni] = *(const short8*)(RB + frB[ni]); \
        __builtin_amdgcn_s_setprio(1); \
        _Pragma("unroll") for (int mi = 0; mi < 4; ++mi) { \
            short8 af = *(const short8*)(RA + frA[mi]); \
            _Pragma("unroll") for (int ni = 0; ni < 4; ++ni) \
                acc[mi][ni] = __builtin_amdgcn_mfma_f32_16x16x32_bf16(af, bfr[ni], acc[mi][ni], 0, 0, 0); \
        } \
        __builtin_amdgcn_s_setprio(0); \
        if (t + 2 < NT) { asm volatile("s_waitcnt vmcnt(3)" ::: "memory"); } \
        else            { asm volatile("s_waitcnt vmcnt(0)" ::: "memory"); } \
        __builtin_amdgcn_s_barrier(); \
        __builtin_amdgcn_sched_barrier(0); \
    }

    int m3 = 0;
    for (int t = 0; t < NT; ++t) {
        if (m3 == 0)      TILEBODY3(As0, Bs0, As2, Bs2)
        else if (m3 == 1) TILEBODY3(As1, Bs1, As0, Bs0)
        else              TILEBODY3(As2, Bs2, As1, Bs1)
        if (++m3 == 3) m3 = 0;
    }
#undef TILEBODY3

    EPILOGUE(tm + wm * 64 + mi * 16 + g * 4 + j, tn + wn * 64 + ni * 16 + l, 4, 4)
}

// ---------------- chunked sliding-window attention (MFMA) ---------------------
#define QS_OFF(r,d0) ((r)*64  + ((((d0)>>3) ^ ((r)&7))  << 3))
#define KS_OFF(j,d0) ((j)*64  + ((((d0)>>3) ^ ((j)&7))  << 3))
#define VT_OFF(d,j0) ((d)*128 + ((((j0)>>3) ^ ((d)&15)) << 3))
#define PS_OFF(r,c0) ((r)*128 + ((((c0)>>3) ^ ((r)&15)) << 3))
__global__ __launch_bounds__(256) void attn_mfma(const unsigned short* __restrict__ qkv,
                                                 unsigned short* __restrict__ ao) {
    __shared__ unsigned short qs[64 * 64];
    __shared__ unsigned short ks[128 * 64];
    __shared__ unsigned short vT[64 * 128];
    __shared__ unsigned short ps[64 * 128];
    int bx = blockIdx.x;
    int c = bx & 63, h = (bx >> 6) & 15, b = bx >> 10;
    int tid = threadIdx.x, lane = tid & 63, w = tid >> 6;
    const int QKV = 3 * Ecst;
    size_t baseq = ((size_t)b * Nn_ + c * 64) * QKV + h * 64;
    size_t baseo = ((size_t)b * Nn_ + c * 64) * Ecst + h * 64;
#pragma unroll
    for (int i = 0; i < 2; ++i) {
        int cc = tid + i * 256;
        int row = cc >> 3, d0 = (cc & 7) * 8;
        short8 vq = *(const short8*)(qkv + baseq + (size_t)row * QKV + d0);
        *(short8*)(qs + QS_OFF(row, d0)) = vq;
    }
#pragma unroll
    for (int i = 0; i < 4; ++i) {
        int cc = tid + i * 256;
        int j = cc >> 3, d0 = (cc & 7) * 8;
        short8 vk = {}; short8 vv = {};
        if (c > 0 || j >= 64) {
            int srcRow = (j < 64) ? (c - 1) * 64 + j : c * 64 + (j - 64);
            size_t sb = ((size_t)b * Nn_ + srcRow) * QKV + h * 64 + d0;
            vk = *(const short8*)(qkv + sb + 1024);
            vv = *(const short8*)(qkv + sb + 2048);
        }
        *(short8*)(ks + KS_OFF(j, d0)) = vk;
#pragma unroll
        for (int u = 0; u < 8; ++u)
            vT[VT_OFF(d0 + u, j & ~7) + (j & 7)] = ((unsigned short*)&vv)[u];
    }
    __syncthreads();
    const int rA = w * 16 + (lane & 15);
    const int ksel = (lane >> 4) * 8;
    f32x4 s[8] = {};
#pragma unroll
    for (int kk = 0; kk < 2; ++kk) {
        short8 aq = *(const short8*)(qs + QS_OFF(rA, kk * 32 + ksel));
#pragma unroll
        for (int ni = 0; ni < 8; ++ni) {
            int j = ni * 16 + (lane & 15);
            short8 bk = *(const short8*)(ks + KS_OFF(j, kk * 32 + ksel));
            s[ni] = __builtin_amdgcn_mfma_f32_16x16x32_bf16(aq, bk, s[ni], 0, 0, 0);
        }
    }
    float inv[4];
    const int rq = (lane >> 4) * 4;
#pragma unroll
    for (int jr = 0; jr < 4; ++jr) {
        int i = w * 16 + rq + jr;
        float vals[8]; float mx = -1e30f;
#pragma unroll
        for (int ni = 0; ni < 8; ++ni) {
            int colw = ni * 16 + (lane & 15);
            bool valid = (colw < 64) || (colw - 64 <= i);
            float vv = valid ? s[ni][jr] * 0.125f : -1e30f;
            vals[ni] = vv;
            mx = fmaxf(mx, vv);
        }
#pragma unroll
        for (int off = 8; off; off >>= 1) mx = fmaxf(mx, __shfl_xor(mx, off));
        float sum = 0.f;
#pragma unroll
        for (int ni = 0; ni < 8; ++ni) {
            float e = (vals[ni] > -1e29f) ? __expf(vals[ni] - mx) : 0.f;
            vals[ni] = e; sum += e;
        }
#pragma unroll
        for (int off = 8; off; off >>= 1) sum += __shfl_xor(sum, off);
        inv[jr] = 1.0f / sum;
        int r = w * 16 + rq + jr;
#pragma unroll
        for (int ni = 0; ni < 8; ++ni) {
            int colw = ni * 16 + (lane & 15);
            ps[PS_OFF(r, colw & ~7) + (colw & 7)] = f2bf(vals[ni]);
        }
    }
    __syncthreads();
    f32x4 o[4] = {};
#pragma unroll
    for (int kk = 0; kk < 4; ++kk) {
        short8 ap = *(const short8*)(ps + PS_OFF(rA, kk * 32 + ksel));
#pragma unroll
        for (int ni = 0; ni < 4; ++ni) {
            int d = ni * 16 + (lane & 15);
            short8 bv = *(const short8*)(vT + VT_OFF(d, kk * 32 + ksel));
            o[ni] = __builtin_amdgcn_mfma_f32_16x16x32_bf16(ap, bv, o[ni], 0, 0, 0);
        }
    }
#pragma unroll
    for (int ni = 0; ni < 4; ++ni) {
#pragma unroll
        for (int jr = 0; jr < 4; ++jr) {
            int row = w * 16 + rq + jr;
            int d = ni * 16 + (lane & 15);
            ao[baseo + (size_t)row * Ecst + d] = f2bf(o[ni][jr] * inv[jr]);
        }
    }
}

// ---------------- loss ---------------------------------------------------------
__global__ __launch_bounds__(256) void loss_partial(const float* __restrict__ x2,
                                                    const float* __restrict__ p,
                                                    float* __restrict__ partials) {
    float s = 0.f;
    for (size_t idx = (size_t)blockIdx.x * 256 + threadIdx.x; idx < BNE / 4; idx += (size_t)gridDim.x * 256) {
        float4 a = *(const float4*)(x2 + idx * 4);
        float4 b = *(const float4*)(p + idx * 4);
        float dx = a.x - b.x, dy = a.y - b.y, dz = a.z - b.z, dw = a.w - b.w;
        s += dx*dx + dy*dy + dz*dz + dw*dw;
    }
#pragma unroll
    for (int off = 32; off; off >>= 1) s += __shfl_xor(s, off);
    __shared__ float sb[4];
    int lane = threadIdx.x & 63, w = threadIdx.x >> 6;
    if (lane == 0) sb[w] = s;
    __syncthreads();
    if (threadIdx.x == 0) partials[blockIdx.x] = sb[0] + sb[1] + sb[2] + sb[3];
}

__global__ __launch_bounds__(256) void loss_final(const float* __restrict__ partials,
                                                  float* __restrict__ out) {
    float s = 0.f;
    for (int i = threadIdx.x; i < 2048; i += 256) s += partials[i];
#pragma unroll
    for (int off = 32; off; off >>= 1) s += __shfl_xor(s, off);
    __shared__ float sb[4];
    int lane = threadIdx.x & 63, w = threadIdx.x >> 6;
    if (lane == 0) sb[w] = s;
    __syncthreads();
    if (threadIdx.x == 0) out[0] = (sb[0] + sb[1] + sb[2] + sb[3]) * (1.0f / (float)BNE);
}

extern "C" void kernel_launch(void* const* d_in, const int* in_sizes, int n_in,
                              void* d_out, int out_size, void* d_ws, size_t ws_size,
                              hipStream_t stream) {
    const float* x     = (const float*)d_in[0];
    const float* p     = (const float*)d_in[1];
    const float* wq    = (const float*)d_in[2];
    const float* bq    = (const float*)d_in[3];
    const float* wk    = (const float*)d_in[4];
    const float* bk    = (const float*)d_in[5];
    const float* wv    = (const float*)d_in[6];
    const float* bv    = (const float*)d_in[7];
    const float* wo    = (const float*)d_in[8];
    const float* bo    = (const float*)d_in[9];
    const float* w1    = (const float*)d_in[10];
    const float* b1    = (const float*)d_in[11];
    const float* w2    = (const float*)d_in[12];
    const float* b2    = (const float*)d_in[13];
    const float* g1    = (const float*)d_in[14];
    const float* beta1 = (const float*)d_in[15];
    const float* g2    = (const float*)d_in[16];
    const float* beta2 = (const float*)d_in[17];

    char* ws = (char*)d_ws;
    size_t off = 0;
    auto alloc = [&](size_t bytes) { void* pp = ws + off; off += (bytes + 255) & ~(size_t)255; return pp; };
    unsigned short* wqkvT = (unsigned short*)alloc((size_t)3 * Ecst * Ecst * 2);
    unsigned short* woT  = (unsigned short*)alloc((size_t)Ecst * Ecst * 2);
    unsigned short* w1T  = (unsigned short*)alloc((size_t)4 * Ecst * Ecst * 2);
    unsigned short* w2T  = (unsigned short*)alloc((size_t)4 * Ecst * Ecst * 2);
    float* bqkv          = (float*)alloc(3 * Ecst * 4);
    unsigned short* xn   = (unsigned short*)alloc((size_t)Mrows * Ecst * 2);  // reused as h after LN2
    unsigned short* qkv  = (unsigned short*)alloc((size_t)Mrows * 3 * Ecst * 2);
    unsigned short* aob  = (unsigned short*)alloc((size_t)Mrows * Ecst * 2);
    unsigned short* ff1  = (unsigned short*)alloc((size_t)Mrows * 4 * Ecst * 2);
    float* partials      = (float*)alloc(2048 * 4);

    float* x1 = (float*)d_out;                    // [0, BNE): x1 then x2 (copy 0)
    float* out2 = (float*)d_out + BNE;            // x2 (copy 1)
    float* lossp = (float*)d_out + 2 * (size_t)BNE;

    const int SMEM256 = 96 * 1024;
    const int SMEM128 = 72 * 1024;
    hipFuncSetAttribute((const void*)gemm256<0, 1024>,  hipFuncAttributeMaxDynamicSharedMemorySize, SMEM256);
    hipFuncSetAttribute((const void*)gemm256<2, 1024>,  hipFuncAttributeMaxDynamicSharedMemorySize, SMEM256);
    hipFuncSetAttribute((const void*)gemm128w<1, 1024>, hipFuncAttributeMaxDynamicSharedMemorySize, SMEM128);
    hipFuncSetAttribute((const void*)gemm128w<3, 4096>, hipFuncAttributeMaxDynamicSharedMemorySize, SMEM128);

    dim3 tb(32, 8);
    transpose_cast<<<dim3(32, 32),  tb, 0, stream>>>(wq, wqkvT, Ecst, Ecst);
    transpose_cast<<<dim3(32, 32),  tb, 0, stream>>>(wk, wqkvT + (size_t)Ecst * Ecst, Ecst, Ecst);
    transpose_cast<<<dim3(32, 32),  tb, 0, stream>>>(wv, wqkvT + (size_t)2 * Ecst * Ecst, Ecst, Ecst);
    transpose_cast<<<dim3(32, 32),  tb, 0, stream>>>(wo, woT, Ecst, Ecst);
    transpose_cast<<<dim3(128, 32), tb, 0, stream>>>(w1, w1T, Ecst, 4 * Ecst);
    transpose_cast<<<dim3(32, 128), tb, 0, stream>>>(w2, w2T, 4 * Ecst, Ecst);
    concat3<<<4, 256, 0, stream>>>(bq, bk, bv, bqkv);

    ln_kernel<<<Mrows, 256, 0, stream>>>(x, g1, beta1, xn);

    // fused QKV: M=16384, N=3072, K=1024  [gemm256 arm]
    gemm256<0, 1024><<<64 * 12, 512, SMEM256, stream>>>(xn, wqkvT, bqkv, 3 * Ecst, 12, qkv, nullptr, nullptr, nullptr);

    attn_mfma<<<Bb * Hh * (Nn_ / Cc_), 256, 0, stream>>>(qkv, aob);

    // WO: M=16384, N=1024, K=1024  [gemm128w arm]
    gemm128w<1, 1024><<<64 * 8, 512, SMEM128, stream>>>(aob, woT, bo, Ecst, 8, nullptr, x1, x, nullptr);

    ln_kernel<<<Mrows, 256, 0, stream>>>(x1, g2, beta2, xn);

    // FFN1: M=16384, N=4096, K=1024  [gemm256 arm]
    gemm256<2, 1024><<<64 * 16, 512, SMEM256, stream>>>(xn, w1T, b1, 4 * Ecst, 16, ff1, nullptr, nullptr, nullptr);

    // FFN2: M=16384, N=1024, K=4096  [gemm128w arm]
    gemm128w<3, 4096><<<64 * 8, 512, SMEM128, stream>>>(ff1, w2T, b2, Ecst, 8, nullptr, x1, x1, out2);

    loss_partial<<<2048, 256, 0, stream>>>((const float*)d_out, p, partials);
    loss_final<<<1, 256, 0, stream>>>(partials, lossp);
}

// Round 6
// 1276.066 us; speedup vs baseline: 1.3281x; 1.0491x over previous
//
#include <hip/hip_runtime.h>
#include <hip/hip_bf16.h>

// Problem constants
#define Ecst 1024
#define Hh 16
#define Dd 64
#define Cc_ 64
#define Bb 4
#define Nn_ 4096
#define Mrows (Bb*Nn_)          // 16384 token rows
#define BNE (Bb*Nn_*Ecst)       // 16,777,216

typedef __attribute__((ext_vector_type(4))) float f32x4;
typedef __attribute__((ext_vector_type(8))) short short8;
typedef __attribute__((ext_vector_type(4))) unsigned short ushort4v;

__device__ __forceinline__ float bf2f(unsigned short u) {
    union { float f; unsigned int i; } x; x.i = ((unsigned int)u) << 16; return x.f;
}
__device__ __forceinline__ unsigned short f2bf(float f) {
    __hip_bfloat16 h = __float2bfloat16(f);
    return *reinterpret_cast<unsigned short*>(&h);
}
// async global->LDS, 16B per lane. lds ptr must be wave-uniform base (+lane*16 implicit).
__device__ __forceinline__ void glds16(const unsigned short* g, unsigned short* l) {
    __builtin_amdgcn_global_load_lds(
        (const __attribute__((address_space(1))) unsigned int*)g,
        (__attribute__((address_space(3))) unsigned int*)l, 16, 0, 0);
}

// ---------------- weight transpose + cast: in [R][C] f32 -> out [C][R] bf16 ----
__global__ __launch_bounds__(256) void transpose_cast(const float* __restrict__ in,
                                                      unsigned short* __restrict__ out,
                                                      int R, int Cc) {
    __shared__ float tile[32][33];
    int c0 = blockIdx.x * 32, r0 = blockIdx.y * 32;
    int tx = threadIdx.x, ty = threadIdx.y;      // block (32,8)
#pragma unroll
    for (int i = 0; i < 4; ++i)
        tile[ty + i*8][tx] = in[(size_t)(r0 + ty + i*8) * Cc + c0 + tx];
    __syncthreads();
#pragma unroll
    for (int i = 0; i < 4; ++i)
        out[(size_t)(c0 + ty + i*8) * R + r0 + tx] = f2bf(tile[tx][ty + i*8]);
}

__global__ __launch_bounds__(256) void concat3(const float* __restrict__ a,
                                               const float* __restrict__ b,
                                               const float* __restrict__ c,
                                               float* __restrict__ o) {
    int i = blockIdx.x * 256 + threadIdx.x;
    if (i < 1024) { o[i] = a[i]; o[1024 + i] = b[i]; o[2048 + i] = c[i]; }
}

// ---------------- LayerNorm: x f32 [rows][1024] -> out bf16 -------------------
__global__ __launch_bounds__(256) void ln_kernel(const float* __restrict__ x,
                                                 const float* __restrict__ g,
                                                 const float* __restrict__ be,
                                                 unsigned short* __restrict__ out) {
    int row = blockIdx.x, tid = threadIdx.x;
    const float4 xv = *(const float4*)(x + (size_t)row * Ecst + tid * 4);
    float s = xv.x + xv.y + xv.z + xv.w;
    float q = xv.x*xv.x + xv.y*xv.y + xv.z*xv.z + xv.w*xv.w;
#pragma unroll
    for (int off = 32; off; off >>= 1) { s += __shfl_xor(s, off); q += __shfl_xor(q, off); }
    __shared__ float sb[8];
    int lane = tid & 63, w = tid >> 6;
    if (lane == 0) { sb[w] = s; sb[4 + w] = q; }
    __syncthreads();
    s = sb[0] + sb[1] + sb[2] + sb[3];
    q = sb[4] + sb[5] + sb[6] + sb[7];
    float mean = s * (1.0f / Ecst);
    float var  = q * (1.0f / Ecst) - mean * mean;
    float rs = rsqrtf(var + 1e-5f);
    ushort4v o;
    const float* xp = (const float*)&xv;
#pragma unroll
    for (int u = 0; u < 4; ++u) {
        float val = (xp[u] - mean) * rs * g[tid*4+u] + be[tid*4+u];
        o[u] = f2bf(val);
    }
    *(ushort4v*)(out + (size_t)row * Ecst + tid * 4) = o;
}

// Common epilogue
#define EPILOGUE(grow_expr, gcol_expr, MREP, NREP) \
    { \
        _Pragma("unroll") for (int mi = 0; mi < MREP; ++mi) { \
        _Pragma("unroll") for (int ni = 0; ni < NREP; ++ni) { \
            int gcol = gcol_expr; \
            float bia = bias[gcol]; \
            _Pragma("unroll") for (int j = 0; j < 4; ++j) { \
                int grow = grow_expr; \
                size_t idx = (size_t)grow * Nc + gcol; \
                float val = acc[mi][ni][j] + bia; \
                if (EPI == 0) { \
                    Ob[idx] = f2bf(val); \
                } else if (EPI == 1) { \
                    Of[idx] = resid[idx] + val; \
                } else if (EPI == 2) { \
                    Ob[idx] = f2bf(0.5f * val * (1.0f + erff(val * 0.70710678118654752f))); \
                } else { \
                    float v2 = resid[idx] + val; \
                    Of[idx] = v2; Of2[idx] = v2; \
                } \
            } \
        } } \
    }

// ---------------- bf16 MFMA GEMM A: 256x256 tile, BK=32, 3-slot LDS ring ------
// Conflict-free (round-3 PMC: SQ_LDS_BANK_CONFLICT == 0). Rounds 3-5: dynamic
// extern __shared__ left the compiler blind to LDS-limited occupancy -> it
// targeted 4 waves/EU -> 128-VGPR cap -> acc[8][4] spilled (0.9-1.3 GB scratch
// WRITE_SIZE). Round-6 fix: STATIC __shared__ 96KB (m201's configuration) so
// the allocator sees 1 block/CU = 2 waves/EU and budgets 256 VGPRs.
template<int EPI, int K>
__global__ __launch_bounds__(512) __attribute__((amdgpu_waves_per_eu(2, 2)))
void gemm256(const unsigned short* __restrict__ A,
             const unsigned short* __restrict__ Bt,
             const float* __restrict__ bias,
             int Nc, int nbn,
             unsigned short* __restrict__ Ob,
             float* __restrict__ Of,
             const float* __restrict__ resid,
             float* __restrict__ Of2) {
    __shared__ unsigned short AsL[3][8192];   // 3 x 16 KB
    __shared__ unsigned short BsL[3][8192];   // 3 x 16 KB
    constexpr int NT = K / 32;
    const int tid = threadIdx.x;
    const int lane = tid & 63, wid = tid >> 6;
    const int wm = wid >> 2, wn = wid & 3;        // wave tile: 128 rows x 64 cols
    const int l = lane & 15, g = lane >> 4;
    const int nwg = gridDim.x, cpx = nwg >> 3;
    const int orig = blockIdx.x;
    const int wg = (orig & 7) * cpx + (orig >> 3);
    const int tm = (wg / nbn) * 256, tn = (wg % nbn) * 256;
    const int c0 = tid, c1 = 512 + tid;
    const int r0 = c0 >> 2, r1 = c1 >> 2;
    const int sg0 = (c0 & 3) ^ ((r0 >> 1) & 3);
    const int sg1 = (c1 & 3) ^ ((r1 >> 1) & 3);
    const size_t aO0 = (size_t)(tm + r0) * K + sg0 * 8;
    const size_t aO1 = (size_t)(tm + r1) * K + sg1 * 8;
    const size_t bO0 = (size_t)(tn + r0) * K + sg0 * 8;
    const size_t bO1 = (size_t)(tn + r1) * K + sg1 * 8;
    const int wls0 = wid * 512;
    const int wls1 = 4096 + wid * 512;
    auto stage = [&](int kt, unsigned short* SA, unsigned short* SB) {
        const unsigned short* gA = A + (size_t)kt * 32;
        const unsigned short* gB = Bt + (size_t)kt * 32;
        glds16(gA + aO0, SA + wls0);
        glds16(gB + bO0, SB + wls0);
        glds16(gA + aO1, SA + wls1);
        glds16(gB + bO1, SB + wls1);
    };
    const int seg = (g ^ ((l >> 1) & 3)) * 8;
    int frA[8], frB[4];
#pragma unroll
    for (int mi = 0; mi < 8; ++mi) frA[mi] = (wm * 128 + mi * 16 + l) * 32 + seg;
#pragma unroll
    for (int ni = 0; ni < 4; ++ni) frB[ni] = (wn * 64 + ni * 16 + l) * 32 + seg;

    f32x4 acc[8][4] = {};
    stage(0, AsL[0], BsL[0]);
    stage(1, AsL[1], BsL[1]);
    asm volatile("s_waitcnt vmcnt(4)" ::: "memory");   // tile 0 landed, tile 1 in flight
    __builtin_amdgcn_s_barrier();
    __builtin_amdgcn_sched_barrier(0);

#define TILEBODY6(RA, RB, SA, SB) \
    { \
        if (t + 2 < NT) stage(t + 2, SA, SB); \
        short8 af[8], bfr[4]; \
        _Pragma("unroll") for (int mi = 0; mi < 8; ++mi) af[mi] = *(const short8*)(RA + frA[mi]); \
        _Pragma("unroll") for (int ni = 0; ni < 4; ++ni) bfr[ni] = *(const short8*)(RB + frB[ni]); \
        __builtin_amdgcn_s_setprio(1); \
        _Pragma("unroll") for (int mi = 0; mi < 8; ++mi) \
        _Pragma("unroll") for (int ni = 0; ni < 4; ++ni) \
            acc[mi][ni] = __builtin_amdgcn_mfma_f32_16x16x32_bf16(af[mi], bfr[ni], acc[mi][ni], 0, 0, 0); \
        __builtin_amdgcn_s_setprio(0); \
        if (t + 2 < NT) { asm volatile("s_waitcnt vmcnt(4)" ::: "memory"); } \
        else            { asm volatile("s_waitcnt vmcnt(0)" ::: "memory"); } \
        __builtin_amdgcn_s_barrier(); \
        __builtin_amdgcn_sched_barrier(0); \
    }

    int m3 = 0;
    for (int t = 0; t < NT; ++t) {
        if (m3 == 0)      TILEBODY6(AsL[0], BsL[0], AsL[2], BsL[2])
        else if (m3 == 1) TILEBODY6(AsL[1], BsL[1], AsL[0], BsL[0])
        else              TILEBODY6(AsL[2], BsL[2], AsL[1], BsL[1])
        if (++m3 == 3) m3 = 0;
    }
#undef TILEBODY6

    EPILOGUE(tm + wm * 128 + mi * 16 + g * 4 + j, tn + wn * 64 + ni * 16 + l, 8, 4)
}

// ---------------- bf16 MFMA GEMM B: 256x128 tile, BK=32, 3-slot LDS ring ------
// Low-pressure arm: 8 waves x 64x64 wave tile -> acc[4][4] = 64 VGPRs; fits a
// 128-VGPR budget without spill. Static 72KB LDS -> 2 blocks/CU possible.
template<int EPI, int K>
__global__ __launch_bounds__(512)
void gemm128w(const unsigned short* __restrict__ A,
              const unsigned short* __restrict__ Bt,
              const float* __restrict__ bias,
              int Nc, int nbn,
              unsigned short* __restrict__ Ob,
              float* __restrict__ Of,
              const float* __restrict__ resid,
              float* __restrict__ Of2) {
    __shared__ unsigned short AsL[3][8192];   // 3 x 16 KB
    __shared__ unsigned short BsL[3][4096];   // 3 x 8 KB
    constexpr int NT = K / 32;
    const int tid = threadIdx.x;
    const int lane = tid & 63, wid = tid >> 6;
    const int wm = wid >> 1, wn = wid & 1;        // wave tile: 64 rows x 64 cols
    const int l = lane & 15, g = lane >> 4;
    const int nwg = gridDim.x, cpx = nwg >> 3;
    const int orig = blockIdx.x;
    const int wg = (orig & 7) * cpx + (orig >> 3);
    const int tm = (wg / nbn) * 256, tn = (wg % nbn) * 128;
    // A: 1024 16B-units (2 sweeps), B: 512 units (1 sweep)
    const int uA0 = tid, uA1 = 512 + tid, uB = tid;
    const int rA0 = uA0 >> 2, rA1 = uA1 >> 2, rB = uB >> 2;
    const int sgA0 = (uA0 & 3) ^ ((rA0 >> 1) & 3);
    const int sgA1 = (uA1 & 3) ^ ((rA1 >> 1) & 3);
    const int sgB  = (uB  & 3) ^ ((rB  >> 1) & 3);
    const size_t aO0 = (size_t)(tm + rA0) * K + sgA0 * 8;
    const size_t aO1 = (size_t)(tm + rA1) * K + sgA1 * 8;
    const size_t bO0 = (size_t)(tn + rB ) * K + sgB  * 8;
    const int wlsA0 = wid * 512, wlsA1 = 4096 + wid * 512, wlsB = wid * 512;
    auto stage = [&](int kt, unsigned short* SA, unsigned short* SB) {
        const unsigned short* gA = A + (size_t)kt * 32;
        const unsigned short* gB = Bt + (size_t)kt * 32;
        glds16(gA + aO0, SA + wlsA0);
        glds16(gA + aO1, SA + wlsA1);
        glds16(gB + bO0, SB + wlsB);
    };
    const int seg = (g ^ ((l >> 1) & 3)) * 8;
    int frA[4], frB[4];
#pragma unroll
    for (int mi = 0; mi < 4; ++mi) frA[mi] = (wm * 64 + mi * 16 + l) * 32 + seg;
#pragma unroll
    for (int ni = 0; ni < 4; ++ni) frB[ni] = (wn * 64 + ni * 16 + l) * 32 + seg;

    f32x4 acc[4][4] = {};
    stage(0, AsL[0], BsL[0]);
    stage(1, AsL[1], BsL[1]);
    asm volatile("s_waitcnt vmcnt(3)" ::: "memory");
    __builtin_amdgcn_s_barrier();
    __builtin_amdgcn_sched_barrier(0);

#define TILEBODY3(RA, RB, SA, SB) \
    { \
        if (t + 2 < NT) stage(t + 2, SA, SB); \
        short8 af[4], bfr[4]; \
        _Pragma("unroll") for (int mi = 0; mi < 4; ++mi) af[mi] = *(const short8*)(RA + frA[mi]); \
        _Pragma("unroll") for (int ni = 0; ni < 4; ++ni) bfr[ni] = *(const short8*)(RB + frB[ni]); \
        __builtin_amdgcn_s_setprio(1); \
        _Pragma("unroll") for (int mi = 0; mi < 4; ++mi) \
        _Pragma("unroll") for (int ni = 0; ni < 4; ++ni) \
            acc[mi][ni] = __builtin_amdgcn_mfma_f32_16x16x32_bf16(af[mi], bfr[ni], acc[mi][ni], 0, 0, 0); \
        __builtin_amdgcn_s_setprio(0); \
        if (t + 2 < NT) { asm volatile("s_waitcnt vmcnt(3)" ::: "memory"); } \
        else            { asm volatile("s_waitcnt vmcnt(0)" ::: "memory"); } \
        __builtin_amdgcn_s_barrier(); \
        __builtin_amdgcn_sched_barrier(0); \
    }

    int m3 = 0;
    for (int t = 0; t < NT; ++t) {
        if (m3 == 0)      TILEBODY3(AsL[0], BsL[0], AsL[2], BsL[2])
        else if (m3 == 1) TILEBODY3(AsL[1], BsL[1], AsL[0], BsL[0])
        else              TILEBODY3(AsL[2], BsL[2], AsL[1], BsL[1])
        if (++m3 == 3) m3 = 0;
    }
#undef TILEBODY3

    EPILOGUE(tm + wm * 64 + mi * 16 + g * 4 + j, tn + wn * 64 + ni * 16 + l, 4, 4)
}

// ---------------- chunked sliding-window attention (MFMA) ---------------------
#define QS_OFF(r,d0) ((r)*64  + ((((d0)>>3) ^ ((r)&7))  << 3))
#define KS_OFF(j,d0) ((j)*64  + ((((d0)>>3) ^ ((j)&7))  << 3))
#define VT_OFF(d,j0) ((d)*128 + ((((j0)>>3) ^ ((d)&15)) << 3))
#define PS_OFF(r,c0) ((r)*128 + ((((c0)>>3) ^ ((r)&15)) << 3))
__global__ __launch_bounds__(256) void attn_mfma(const unsigned short* __restrict__ qkv,
                                                 unsigned short* __restrict__ ao) {
    __shared__ unsigned short qs[64 * 64];
    __shared__ unsigned short ks[128 * 64];
    __shared__ unsigned short vT[64 * 128];
    __shared__ unsigned short ps[64 * 128];
    int bx = blockIdx.x;
    int c = bx & 63, h = (bx >> 6) & 15, b = bx >> 10;
    int tid = threadIdx.x, lane = tid & 63, w = tid >> 6;
    const int QKV = 3 * Ecst;
    size_t baseq = ((size_t)b * Nn_ + c * 64) * QKV + h * 64;
    size_t baseo = ((size_t)b * Nn_ + c * 64) * Ecst + h * 64;
#pragma unroll
    for (int i = 0; i < 2; ++i) {
        int cc = tid + i * 256;
        int row = cc >> 3, d0 = (cc & 7) * 8;
        short8 vq = *(const short8*)(qkv + baseq + (size_t)row * QKV + d0);
        *(short8*)(qs + QS_OFF(row, d0)) = vq;
    }
#pragma unroll
    for (int i = 0; i < 4; ++i) {
        int cc = tid + i * 256;
        int j = cc >> 3, d0 = (cc & 7) * 8;
        short8 vk = {}; short8 vv = {};
        if (c > 0 || j >= 64) {
            int srcRow = (j < 64) ? (c - 1) * 64 + j : c * 64 + (j - 64);
            size_t sb = ((size_t)b * Nn_ + srcRow) * QKV + h * 64 + d0;
            vk = *(const short8*)(qkv + sb + 1024);
            vv = *(const short8*)(qkv + sb + 2048);
        }
        *(short8*)(ks + KS_OFF(j, d0)) = vk;
#pragma unroll
        for (int u = 0; u < 8; ++u)
            vT[VT_OFF(d0 + u, j & ~7) + (j & 7)] = ((unsigned short*)&vv)[u];
    }
    __syncthreads();
    const int rA = w * 16 + (lane & 15);
    const int ksel = (lane >> 4) * 8;
    f32x4 s[8] = {};
#pragma unroll
    for (int kk = 0; kk < 2; ++kk) {
        short8 aq = *(const short8*)(qs + QS_OFF(rA, kk * 32 + ksel));
#pragma unroll
        for (int ni = 0; ni < 8; ++ni) {
            int j = ni * 16 + (lane & 15);
            short8 bk = *(const short8*)(ks + KS_OFF(j, kk * 32 + ksel));
            s[ni] = __builtin_amdgcn_mfma_f32_16x16x32_bf16(aq, bk, s[ni], 0, 0, 0);
        }
    }
    float inv[4];
    const int rq = (lane >> 4) * 4;
#pragma unroll
    for (int jr = 0; jr < 4; ++jr) {
        int i = w * 16 + rq + jr;
        float vals[8]; float mx = -1e30f;
#pragma unroll
        for (int ni = 0; ni < 8; ++ni) {
            int colw = ni * 16 + (lane & 15);
            bool valid = (colw < 64) || (colw - 64 <= i);
            float vv = valid ? s[ni][jr] * 0.125f : -1e30f;
            vals[ni] = vv;
            mx = fmaxf(mx, vv);
        }
#pragma unroll
        for (int off = 8; off; off >>= 1) mx = fmaxf(mx, __shfl_xor(mx, off));
        float sum = 0.f;
#pragma unroll
        for (int ni = 0; ni < 8; ++ni) {
            float e = (vals[ni] > -1e29f) ? __expf(vals[ni] - mx) : 0.f;
            vals[ni] = e; sum += e;
        }
#pragma unroll
        for (int off = 8; off; off >>= 1) sum += __shfl_xor(sum, off);
        inv[jr] = 1.0f / sum;
        int r = w * 16 + rq + jr;
#pragma unroll
        for (int ni = 0; ni < 8; ++ni) {
            int colw = ni * 16 + (lane & 15);
            ps[PS_OFF(r, colw & ~7) + (colw & 7)] = f2bf(vals[ni]);
        }
    }
    __syncthreads();
    f32x4 o[4] = {};
#pragma unroll
    for (int kk = 0; kk < 4; ++kk) {
        short8 ap = *(const short8*)(ps + PS_OFF(rA, kk * 32 + ksel));
#pragma unroll
        for (int ni = 0; ni < 4; ++ni) {
            int d = ni * 16 + (lane & 15);
            short8 bv = *(const short8*)(vT + VT_OFF(d, kk * 32 + ksel));
            o[ni] = __builtin_amdgcn_mfma_f32_16x16x32_bf16(ap, bv, o[ni], 0, 0, 0);
        }
    }
#pragma unroll
    for (int ni = 0; ni < 4; ++ni) {
#pragma unroll
        for (int jr = 0; jr < 4; ++jr) {
            int row = w * 16 + rq + jr;
            int d = ni * 16 + (lane & 15);
            ao[baseo + (size_t)row * Ecst + d] = f2bf(o[ni][jr] * inv[jr]);
        }
    }
}

// ---------------- loss ---------------------------------------------------------
__global__ __launch_bounds__(256) void loss_partial(const float* __restrict__ x2,
                                                    const float* __restrict__ p,
                                                    float* __restrict__ partials) {
    float s = 0.f;
    for (size_t idx = (size_t)blockIdx.x * 256 + threadIdx.x; idx < BNE / 4; idx += (size_t)gridDim.x * 256) {
        float4 a = *(const float4*)(x2 + idx * 4);
        float4 b = *(const float4*)(p + idx * 4);
        float dx = a.x - b.x, dy = a.y - b.y, dz = a.z - b.z, dw = a.w - b.w;
        s += dx*dx + dy*dy + dz*dz + dw*dw;
    }
#pragma unroll
    for (int off = 32; off; off >>= 1) s += __shfl_xor(s, off);
    __shared__ float sb[4];
    int lane = threadIdx.x & 63, w = threadIdx.x >> 6;
    if (lane == 0) sb[w] = s;
    __syncthreads();
    if (threadIdx.x == 0) partials[blockIdx.x] = sb[0] + sb[1] + sb[2] + sb[3];
}

__global__ __launch_bounds__(256) void loss_final(const float* __restrict__ partials,
                                                  float* __restrict__ out) {
    float s = 0.f;
    for (int i = threadIdx.x; i < 2048; i += 256) s += partials[i];
#pragma unroll
    for (int off = 32; off; off >>= 1) s += __shfl_xor(s, off);
    __shared__ float sb[4];
    int lane = threadIdx.x & 63, w = threadIdx.x >> 6;
    if (lane == 0) sb[w] = s;
    __syncthreads();
    if (threadIdx.x == 0) out[0] = (sb[0] + sb[1] + sb[2] + sb[3]) * (1.0f / (float)BNE);
}

extern "C" void kernel_launch(void* const* d_in, const int* in_sizes, int n_in,
                              void* d_out, int out_size, void* d_ws, size_t ws_size,
                              hipStream_t stream) {
    const float* x     = (const float*)d_in[0];
    const float* p     = (const float*)d_in[1];
    const float* wq    = (const float*)d_in[2];
    const float* bq    = (const float*)d_in[3];
    const float* wk    = (const float*)d_in[4];
    const float* bk    = (const float*)d_in[5];
    const float* wv    = (const float*)d_in[6];
    const float* bv    = (const float*)d_in[7];
    const float* wo    = (const float*)d_in[8];
    const float* bo    = (const float*)d_in[9];
    const float* w1    = (const float*)d_in[10];
    const float* b1    = (const float*)d_in[11];
    const float* w2    = (const float*)d_in[12];
    const float* b2    = (const float*)d_in[13];
    const float* g1    = (const float*)d_in[14];
    const float* beta1 = (const float*)d_in[15];
    const float* g2    = (const float*)d_in[16];
    const float* beta2 = (const float*)d_in[17];

    char* ws = (char*)d_ws;
    size_t off = 0;
    auto alloc = [&](size_t bytes) { void* pp = ws + off; off += (bytes + 255) & ~(size_t)255; return pp; };
    unsigned short* wqkvT = (unsigned short*)alloc((size_t)3 * Ecst * Ecst * 2);
    unsigned short* woT  = (unsigned short*)alloc((size_t)Ecst * Ecst * 2);
    unsigned short* w1T  = (unsigned short*)alloc((size_t)4 * Ecst * Ecst * 2);
    unsigned short* w2T  = (unsigned short*)alloc((size_t)4 * Ecst * Ecst * 2);
    float* bqkv          = (float*)alloc(3 * Ecst * 4);
    unsigned short* xn   = (unsigned short*)alloc((size_t)Mrows * Ecst * 2);  // reused as h after LN2
    unsigned short* qkv  = (unsigned short*)alloc((size_t)Mrows * 3 * Ecst * 2);
    unsigned short* aob  = (unsigned short*)alloc((size_t)Mrows * Ecst * 2);
    unsigned short* ff1  = (unsigned short*)alloc((size_t)Mrows * 4 * Ecst * 2);
    float* partials      = (float*)alloc(2048 * 4);

    float* x1 = (float*)d_out;                    // [0, BNE): x1 then x2 (copy 0)
    float* out2 = (float*)d_out + BNE;            // x2 (copy 1)
    float* lossp = (float*)d_out + 2 * (size_t)BNE;

    dim3 tb(32, 8);
    transpose_cast<<<dim3(32, 32),  tb, 0, stream>>>(wq, wqkvT, Ecst, Ecst);
    transpose_cast<<<dim3(32, 32),  tb, 0, stream>>>(wk, wqkvT + (size_t)Ecst * Ecst, Ecst, Ecst);
    transpose_cast<<<dim3(32, 32),  tb, 0, stream>>>(wv, wqkvT + (size_t)2 * Ecst * Ecst, Ecst, Ecst);
    transpose_cast<<<dim3(32, 32),  tb, 0, stream>>>(wo, woT, Ecst, Ecst);
    transpose_cast<<<dim3(128, 32), tb, 0, stream>>>(w1, w1T, Ecst, 4 * Ecst);
    transpose_cast<<<dim3(32, 128), tb, 0, stream>>>(w2, w2T, 4 * Ecst, Ecst);
    concat3<<<4, 256, 0, stream>>>(bq, bk, bv, bqkv);

    ln_kernel<<<Mrows, 256, 0, stream>>>(x, g1, beta1, xn);

    // fused QKV: M=16384, N=3072, K=1024  [gemm256 arm]
    gemm256<0, 1024><<<64 * 12, 512, 0, stream>>>(xn, wqkvT, bqkv, 3 * Ecst, 12, qkv, nullptr, nullptr, nullptr);

    attn_mfma<<<Bb * Hh * (Nn_ / Cc_), 256, 0, stream>>>(qkv, aob);

    // WO: M=16384, N=1024, K=1024  [gemm128w arm]
    gemm128w<1, 1024><<<64 * 8, 512, 0, stream>>>(aob, woT, bo, Ecst, 8, nullptr, x1, x, nullptr);

    ln_kernel<<<Mrows, 256, 0, stream>>>(x1, g2, beta2, xn);

    // FFN1: M=16384, N=4096, K=1024  [gemm256 arm]
    gemm256<2, 1024><<<64 * 16, 512, 0, stream>>>(xn, w1T, b1, 4 * Ecst, 16, ff1, nullptr, nullptr, nullptr);

    // FFN2: M=16384, N=1024, K=4096  [gemm128w arm]
    gemm128w<3, 4096><<<64 * 8, 512, 0, stream>>>(ff1, w2T, b2, Ecst, 8, nullptr, x1, x1, out2);

    loss_partial<<<2048, 256, 0, stream>>>((const float*)d_out, p, partials);
    loss_final<<<1, 256, 0, stream>>>(partials, lossp);
}

// Round 7
// 978.758 us; speedup vs baseline: 1.7316x; 1.3038x over previous
//
#include <hip/hip_runtime.h>
#include <hip/hip_bf16.h>

// Problem constants
#define Ecst 1024
#define Hh 16
#define Dd 64
#define Cc_ 64
#define Bb 4
#define Nn_ 4096
#define Mrows (Bb*Nn_)          // 16384 token rows
#define BNE (Bb*Nn_*Ecst)       // 16,777,216

typedef __attribute__((ext_vector_type(4))) float f32x4;
typedef __attribute__((ext_vector_type(8))) short short8;
typedef __attribute__((ext_vector_type(4))) unsigned short ushort4v;

__device__ __forceinline__ float bf2f(unsigned short u) {
    union { float f; unsigned int i; } x; x.i = ((unsigned int)u) << 16; return x.f;
}
__device__ __forceinline__ unsigned short f2bf(float f) {
    __hip_bfloat16 h = __float2bfloat16(f);
    return *reinterpret_cast<unsigned short*>(&h);
}
// async global->LDS, 16B per lane. lds ptr must be wave-uniform base (+lane*16 implicit).
__device__ __forceinline__ void glds16(const unsigned short* g, unsigned short* l) {
    __builtin_amdgcn_global_load_lds(
        (const __attribute__((address_space(1))) unsigned int*)g,
        (__attribute__((address_space(3))) unsigned int*)l, 16, 0, 0);
}

// ---------------- weight transpose + cast: in [R][C] f32 -> out [C][R] bf16 ----
__global__ __launch_bounds__(256) void transpose_cast(const float* __restrict__ in,
                                                      unsigned short* __restrict__ out,
                                                      int R, int Cc) {
    __shared__ float tile[32][33];
    int c0 = blockIdx.x * 32, r0 = blockIdx.y * 32;
    int tx = threadIdx.x, ty = threadIdx.y;      // block (32,8)
#pragma unroll
    for (int i = 0; i < 4; ++i)
        tile[ty + i*8][tx] = in[(size_t)(r0 + ty + i*8) * Cc + c0 + tx];
    __syncthreads();
#pragma unroll
    for (int i = 0; i < 4; ++i)
        out[(size_t)(c0 + ty + i*8) * R + r0 + tx] = f2bf(tile[tx][ty + i*8]);
}

__global__ __launch_bounds__(256) void concat3(const float* __restrict__ a,
                                               const float* __restrict__ b,
                                               const float* __restrict__ c,
                                               float* __restrict__ o) {
    int i = blockIdx.x * 256 + threadIdx.x;
    if (i < 1024) { o[i] = a[i]; o[1024 + i] = b[i]; o[2048 + i] = c[i]; }
}

// ---------------- LayerNorm: x f32 [rows][1024] -> out bf16 -------------------
__global__ __launch_bounds__(256) void ln_kernel(const float* __restrict__ x,
                                                 const float* __restrict__ g,
                                                 const float* __restrict__ be,
                                                 unsigned short* __restrict__ out) {
    int row = blockIdx.x, tid = threadIdx.x;
    const float4 xv = *(const float4*)(x + (size_t)row * Ecst + tid * 4);
    float s = xv.x + xv.y + xv.z + xv.w;
    float q = xv.x*xv.x + xv.y*xv.y + xv.z*xv.z + xv.w*xv.w;
#pragma unroll
    for (int off = 32; off; off >>= 1) { s += __shfl_xor(s, off); q += __shfl_xor(q, off); }
    __shared__ float sb[8];
    int lane = tid & 63, w = tid >> 6;
    if (lane == 0) { sb[w] = s; sb[4 + w] = q; }
    __syncthreads();
    s = sb[0] + sb[1] + sb[2] + sb[3];
    q = sb[4] + sb[5] + sb[6] + sb[7];
    float mean = s * (1.0f / Ecst);
    float var  = q * (1.0f / Ecst) - mean * mean;
    float rs = rsqrtf(var + 1e-5f);
    ushort4v o;
    const float* xp = (const float*)&xv;
#pragma unroll
    for (int u = 0; u < 4; ++u) {
        float val = (xp[u] - mean) * rs * g[tid*4+u] + be[tid*4+u];
        o[u] = f2bf(val);
    }
    *(ushort4v*)(out + (size_t)row * Ecst + tid * 4) = o;
}

// Common epilogue
#define EPILOGUE(grow_expr, gcol_expr, MREP, NREP) \
    { \
        _Pragma("unroll") for (int mi = 0; mi < MREP; ++mi) { \
        _Pragma("unroll") for (int ni = 0; ni < NREP; ++ni) { \
            int gcol = gcol_expr; \
            float bia = bias[gcol]; \
            _Pragma("unroll") for (int j = 0; j < 4; ++j) { \
                int grow = grow_expr; \
                size_t idx = (size_t)grow * Nc + gcol; \
                float val = acc[mi][ni][j] + bia; \
                if (EPI == 0) { \
                    Ob[idx] = f2bf(val); \
                } else if (EPI == 1) { \
                    Of[idx] = resid[idx] + val; \
                } else if (EPI == 2) { \
                    Ob[idx] = f2bf(0.5f * val * (1.0f + erff(val * 0.70710678118654752f))); \
                } else { \
                    float v2 = resid[idx] + val; \
                    Of[idx] = v2; Of2[idx] = v2; \
                } \
            } \
        } } \
    }

// ---------------- bf16 MFMA GEMM (8-wave): 256x128 tile, BK=32, 3-slot ring ---
// The proven no-spill workhorse (ran WO+FFN2 rounds 5-6 correctly). 8 waves x
// 64x64 wave tile -> acc[4][4] = 64 VGPRs, fits the 512-thread 128-VGPR budget
// (rounds 3-6: 512-thread kernels are hard-capped at 128 VGPRs regardless of
// launch_bounds / waves_per_eu / static LDS -> acc[8][4] always spilled).
// T2 both-sides swizzle (round-3 PMC: 0 bank conflicts), T4 counted vmcnt(3),
// T1 XCD swizzle, T5 setprio.
template<int EPI, int K>
__global__ __launch_bounds__(512)
void gemm128w(const unsigned short* __restrict__ A,
              const unsigned short* __restrict__ Bt,
              const float* __restrict__ bias,
              int Nc, int nbn,
              unsigned short* __restrict__ Ob,
              float* __restrict__ Of,
              const float* __restrict__ resid,
              float* __restrict__ Of2) {
    __shared__ unsigned short AsL[3][8192];   // 3 x 16 KB (256 rows x 32)
    __shared__ unsigned short BsL[3][4096];   // 3 x 8 KB  (128 rows x 32)
    constexpr int NT = K / 32;
    const int tid = threadIdx.x;
    const int lane = tid & 63, wid = tid >> 6;
    const int wm = wid >> 1, wn = wid & 1;        // wave tile: 64 rows x 64 cols
    const int l = lane & 15, g = lane >> 4;
    const int nwg = gridDim.x, cpx = nwg >> 3;
    const int orig = blockIdx.x;
    const int wg = (orig & 7) * cpx + (orig >> 3);
    const int tm = (wg / nbn) * 256, tn = (wg % nbn) * 128;
    // A: 1024 16B-units (2 sweeps), B: 512 units (1 sweep)
    const int uA0 = tid, uA1 = 512 + tid, uB = tid;
    const int rA0 = uA0 >> 2, rA1 = uA1 >> 2, rB = uB >> 2;
    const int sgA0 = (uA0 & 3) ^ ((rA0 >> 1) & 3);
    const int sgA1 = (uA1 & 3) ^ ((rA1 >> 1) & 3);
    const int sgB  = (uB  & 3) ^ ((rB  >> 1) & 3);
    const size_t aO0 = (size_t)(tm + rA0) * K + sgA0 * 8;
    const size_t aO1 = (size_t)(tm + rA1) * K + sgA1 * 8;
    const size_t bO0 = (size_t)(tn + rB ) * K + sgB  * 8;
    const int wlsA0 = wid * 512, wlsA1 = 4096 + wid * 512, wlsB = wid * 512;
    auto stage = [&](int kt, unsigned short* SA, unsigned short* SB) {
        const unsigned short* gA = A + (size_t)kt * 32;
        const unsigned short* gB = Bt + (size_t)kt * 32;
        glds16(gA + aO0, SA + wlsA0);
        glds16(gA + aO1, SA + wlsA1);
        glds16(gB + bO0, SB + wlsB);
    };
    const int seg = (g ^ ((l >> 1) & 3)) * 8;
    int frA[4], frB[4];
#pragma unroll
    for (int mi = 0; mi < 4; ++mi) frA[mi] = (wm * 64 + mi * 16 + l) * 32 + seg;
#pragma unroll
    for (int ni = 0; ni < 4; ++ni) frB[ni] = (wn * 64 + ni * 16 + l) * 32 + seg;

    f32x4 acc[4][4] = {};
    stage(0, AsL[0], BsL[0]);
    stage(1, AsL[1], BsL[1]);
    asm volatile("s_waitcnt vmcnt(3)" ::: "memory");
    __builtin_amdgcn_s_barrier();
    __builtin_amdgcn_sched_barrier(0);

#define TILEBODY3(RA, RB, SA, SB) \
    { \
        if (t + 2 < NT) stage(t + 2, SA, SB); \
        short8 af[4], bfr[4]; \
        _Pragma("unroll") for (int mi = 0; mi < 4; ++mi) af[mi] = *(const short8*)(RA + frA[mi]); \
        _Pragma("unroll") for (int ni = 0; ni < 4; ++ni) bfr[ni] = *(const short8*)(RB + frB[ni]); \
        __builtin_amdgcn_s_setprio(1); \
        _Pragma("unroll") for (int mi = 0; mi < 4; ++mi) \
        _Pragma("unroll") for (int ni = 0; ni < 4; ++ni) \
            acc[mi][ni] = __builtin_amdgcn_mfma_f32_16x16x32_bf16(af[mi], bfr[ni], acc[mi][ni], 0, 0, 0); \
        __builtin_amdgcn_s_setprio(0); \
        if (t + 2 < NT) { asm volatile("s_waitcnt vmcnt(3)" ::: "memory"); } \
        else            { asm volatile("s_waitcnt vmcnt(0)" ::: "memory"); } \
        __builtin_amdgcn_s_barrier(); \
        __builtin_amdgcn_sched_barrier(0); \
    }

    int m3 = 0;
    for (int t = 0; t < NT; ++t) {
        if (m3 == 0)      TILEBODY3(AsL[0], BsL[0], AsL[2], BsL[2])
        else if (m3 == 1) TILEBODY3(AsL[1], BsL[1], AsL[0], BsL[0])
        else              TILEBODY3(AsL[2], BsL[2], AsL[1], BsL[1])
        if (++m3 == 3) m3 = 0;
    }
#undef TILEBODY3

    EPILOGUE(tm + wm * 64 + mi * 16 + g * 4 + j, tn + wn * 64 + ni * 16 + l, 4, 4)
}

// ---------------- bf16 MFMA GEMM probe (4-wave): 256x128 tile, acc[8][4] ------
// Tests whether the 128-VGPR cap is thread-count-dependent: 256-thread blocks
// previously got free budgets (round-2: VGPR=100; m97 precedent: 164). Needs
// ~190 VGPRs for acc[8][4]=128 + frags + addresses. 72KB LDS -> 2 blocks/CU.
// Deployed ONLY on WO (34 GF) to bound the damage if it spills.
template<int EPI, int K>
__global__ __launch_bounds__(256)
void gemm4w(const unsigned short* __restrict__ A,
            const unsigned short* __restrict__ Bt,
            const float* __restrict__ bias,
            int Nc, int nbn,
            unsigned short* __restrict__ Ob,
            float* __restrict__ Of,
            const float* __restrict__ resid,
            float* __restrict__ Of2) {
    __shared__ unsigned short AsL[3][8192];   // 256 x 32
    __shared__ unsigned short BsL[3][4096];   // 128 x 32
    constexpr int NT = K / 32;
    const int tid = threadIdx.x;
    const int lane = tid & 63, wid = tid >> 6;    // 4 waves
    const int wm = wid >> 1, wn = wid & 1;        // wave tile: 128 rows x 64 cols
    const int l = lane & 15, g = lane >> 4;
    const int nwg = gridDim.x, cpx = nwg >> 3;
    const int orig = blockIdx.x;
    const int wg = (orig & 7) * cpx + (orig >> 3);
    const int tm = (wg / nbn) * 256, tn = (wg % nbn) * 128;
    // A: 1024 16B-units in 4 sweeps; B: 512 units in 2 sweeps (256 threads)
    size_t aO[4]; size_t bO[2];
#pragma unroll
    for (int s = 0; s < 4; ++s) {
        int u = s * 256 + tid, r = u >> 2;
        int sg = (u & 3) ^ ((r >> 1) & 3);
        aO[s] = (size_t)(tm + r) * K + sg * 8;
    }
#pragma unroll
    for (int s = 0; s < 2; ++s) {
        int u = s * 256 + tid, r = u >> 2;
        int sg = (u & 3) ^ ((r >> 1) & 3);
        bO[s] = (size_t)(tn + r) * K + sg * 8;
    }
    const int wbase = wid * 512;
    auto stage = [&](int kt, unsigned short* SA, unsigned short* SB) {
        const unsigned short* gA = A + (size_t)kt * 32;
        const unsigned short* gB = Bt + (size_t)kt * 32;
#pragma unroll
        for (int s = 0; s < 4; ++s) glds16(gA + aO[s], SA + s * 2048 + wbase);
#pragma unroll
        for (int s = 0; s < 2; ++s) glds16(gB + bO[s], SB + s * 2048 + wbase);
    };
    const int seg = (g ^ ((l >> 1) & 3)) * 8;
    int frA[8], frB[4];
#pragma unroll
    for (int mi = 0; mi < 8; ++mi) frA[mi] = (wm * 128 + mi * 16 + l) * 32 + seg;
#pragma unroll
    for (int ni = 0; ni < 4; ++ni) frB[ni] = (wn * 64 + ni * 16 + l) * 32 + seg;

    f32x4 acc[8][4] = {};
    stage(0, AsL[0], BsL[0]);
    stage(1, AsL[1], BsL[1]);
    asm volatile("s_waitcnt vmcnt(6)" ::: "memory");
    __builtin_amdgcn_s_barrier();
    __builtin_amdgcn_sched_barrier(0);

#define TILEBODY6W(RA, RB, SA, SB) \
    { \
        if (t + 2 < NT) stage(t + 2, SA, SB); \
        short8 bfr[4]; \
        _Pragma("unroll") for (int ni = 0; ni < 4; ++ni) bfr[ni] = *(const short8*)(RB + frB[ni]); \
        __builtin_amdgcn_s_setprio(1); \
        _Pragma("unroll") for (int mi = 0; mi < 8; ++mi) { \
            short8 af = *(const short8*)(RA + frA[mi]); \
            _Pragma("unroll") for (int ni = 0; ni < 4; ++ni) \
                acc[mi][ni] = __builtin_amdgcn_mfma_f32_16x16x32_bf16(af, bfr[ni], acc[mi][ni], 0, 0, 0); \
        } \
        __builtin_amdgcn_s_setprio(0); \
        if (t + 2 < NT) { asm volatile("s_waitcnt vmcnt(6)" ::: "memory"); } \
        else            { asm volatile("s_waitcnt vmcnt(0)" ::: "memory"); } \
        __builtin_amdgcn_s_barrier(); \
        __builtin_amdgcn_sched_barrier(0); \
    }

    int m3 = 0;
    for (int t = 0; t < NT; ++t) {
        if (m3 == 0)      TILEBODY6W(AsL[0], BsL[0], AsL[2], BsL[2])
        else if (m3 == 1) TILEBODY6W(AsL[1], BsL[1], AsL[0], BsL[0])
        else              TILEBODY6W(AsL[2], BsL[2], AsL[1], BsL[1])
        if (++m3 == 3) m3 = 0;
    }
#undef TILEBODY6W

    EPILOGUE(tm + wm * 128 + mi * 16 + g * 4 + j, tn + wn * 64 + ni * 16 + l, 8, 4)
}

// ---------------- chunked sliding-window attention (MFMA) ---------------------
#define QS_OFF(r,d0) ((r)*64  + ((((d0)>>3) ^ ((r)&7))  << 3))
#define KS_OFF(j,d0) ((j)*64  + ((((d0)>>3) ^ ((j)&7))  << 3))
#define VT_OFF(d,j0) ((d)*128 + ((((j0)>>3) ^ ((d)&15)) << 3))
#define PS_OFF(r,c0) ((r)*128 + ((((c0)>>3) ^ ((r)&15)) << 3))
__global__ __launch_bounds__(256) void attn_mfma(const unsigned short* __restrict__ qkv,
                                                 unsigned short* __restrict__ ao) {
    __shared__ unsigned short qs[64 * 64];
    __shared__ unsigned short ks[128 * 64];
    __shared__ unsigned short vT[64 * 128];
    __shared__ unsigned short ps[64 * 128];
    int bx = blockIdx.x;
    int c = bx & 63, h = (bx >> 6) & 15, b = bx >> 10;
    int tid = threadIdx.x, lane = tid & 63, w = tid >> 6;
    const int QKV = 3 * Ecst;
    size_t baseq = ((size_t)b * Nn_ + c * 64) * QKV + h * 64;
    size_t baseo = ((size_t)b * Nn_ + c * 64) * Ecst + h * 64;
#pragma unroll
    for (int i = 0; i < 2; ++i) {
        int cc = tid + i * 256;
        int row = cc >> 3, d0 = (cc & 7) * 8;
        short8 vq = *(const short8*)(qkv + baseq + (size_t)row * QKV + d0);
        *(short8*)(qs + QS_OFF(row, d0)) = vq;
    }
#pragma unroll
    for (int i = 0; i < 4; ++i) {
        int cc = tid + i * 256;
        int j = cc >> 3, d0 = (cc & 7) * 8;
        short8 vk = {}; short8 vv = {};
        if (c > 0 || j >= 64) {
            int srcRow = (j < 64) ? (c - 1) * 64 + j : c * 64 + (j - 64);
            size_t sb = ((size_t)b * Nn_ + srcRow) * QKV + h * 64 + d0;
            vk = *(const short8*)(qkv + sb + 1024);
            vv = *(const short8*)(qkv + sb + 2048);
        }
        *(short8*)(ks + KS_OFF(j, d0)) = vk;
#pragma unroll
        for (int u = 0; u < 8; ++u)
            vT[VT_OFF(d0 + u, j & ~7) + (j & 7)] = ((unsigned short*)&vv)[u];
    }
    __syncthreads();
    const int rA = w * 16 + (lane & 15);
    const int ksel = (lane >> 4) * 8;
    f32x4 s[8] = {};
#pragma unroll
    for (int kk = 0; kk < 2; ++kk) {
        short8 aq = *(const short8*)(qs + QS_OFF(rA, kk * 32 + ksel));
#pragma unroll
        for (int ni = 0; ni < 8; ++ni) {
            int j = ni * 16 + (lane & 15);
            short8 bk = *(const short8*)(ks + KS_OFF(j, kk * 32 + ksel));
            s[ni] = __builtin_amdgcn_mfma_f32_16x16x32_bf16(aq, bk, s[ni], 0, 0, 0);
        }
    }
    float inv[4];
    const int rq = (lane >> 4) * 4;
#pragma unroll
    for (int jr = 0; jr < 4; ++jr) {
        int i = w * 16 + rq + jr;
        float vals[8]; float mx = -1e30f;
#pragma unroll
        for (int ni = 0; ni < 8; ++ni) {
            int colw = ni * 16 + (lane & 15);
            bool valid = (colw < 64) || (colw - 64 <= i);
            float vv = valid ? s[ni][jr] * 0.125f : -1e30f;
            vals[ni] = vv;
            mx = fmaxf(mx, vv);
        }
#pragma unroll
        for (int off = 8; off; off >>= 1) mx = fmaxf(mx, __shfl_xor(mx, off));
        float sum = 0.f;
#pragma unroll
        for (int ni = 0; ni < 8; ++ni) {
            float e = (vals[ni] > -1e29f) ? __expf(vals[ni] - mx) : 0.f;
            vals[ni] = e; sum += e;
        }
#pragma unroll
        for (int off = 8; off; off >>= 1) sum += __shfl_xor(sum, off);
        inv[jr] = 1.0f / sum;
        int r = w * 16 + rq + jr;
#pragma unroll
        for (int ni = 0; ni < 8; ++ni) {
            int colw = ni * 16 + (lane & 15);
            ps[PS_OFF(r, colw & ~7) + (colw & 7)] = f2bf(vals[ni]);
        }
    }
    __syncthreads();
    f32x4 o[4] = {};
#pragma unroll
    for (int kk = 0; kk < 4; ++kk) {
        short8 ap = *(const short8*)(ps + PS_OFF(rA, kk * 32 + ksel));
#pragma unroll
        for (int ni = 0; ni < 4; ++ni) {
            int d = ni * 16 + (lane & 15);
            short8 bv = *(const short8*)(vT + VT_OFF(d, kk * 32 + ksel));
            o[ni] = __builtin_amdgcn_mfma_f32_16x16x32_bf16(ap, bv, o[ni], 0, 0, 0);
        }
    }
#pragma unroll
    for (int ni = 0; ni < 4; ++ni) {
#pragma unroll
        for (int jr = 0; jr < 4; ++jr) {
            int row = w * 16 + rq + jr;
            int d = ni * 16 + (lane & 15);
            ao[baseo + (size_t)row * Ecst + d] = f2bf(o[ni][jr] * inv[jr]);
        }
    }
}

// ---------------- loss ---------------------------------------------------------
__global__ __launch_bounds__(256) void loss_partial(const float* __restrict__ x2,
                                                    const float* __restrict__ p,
                                                    float* __restrict__ partials) {
    float s = 0.f;
    for (size_t idx = (size_t)blockIdx.x * 256 + threadIdx.x; idx < BNE / 4; idx += (size_t)gridDim.x * 256) {
        float4 a = *(const float4*)(x2 + idx * 4);
        float4 b = *(const float4*)(p + idx * 4);
        float dx = a.x - b.x, dy = a.y - b.y, dz = a.z - b.z, dw = a.w - b.w;
        s += dx*dx + dy*dy + dz*dz + dw*dw;
    }
#pragma unroll
    for (int off = 32; off; off >>= 1) s += __shfl_xor(s, off);
    __shared__ float sb[4];
    int lane = threadIdx.x & 63, w = threadIdx.x >> 6;
    if (lane == 0) sb[w] = s;
    __syncthreads();
    if (threadIdx.x == 0) partials[blockIdx.x] = sb[0] + sb[1] + sb[2] + sb[3];
}

__global__ __launch_bounds__(256) void loss_final(const float* __restrict__ partials,
                                                  float* __restrict__ out) {
    float s = 0.f;
    for (int i = threadIdx.x; i < 2048; i += 256) s += partials[i];
#pragma unroll
    for (int off = 32; off; off >>= 1) s += __shfl_xor(s, off);
    __shared__ float sb[4];
    int lane = threadIdx.x & 63, w = threadIdx.x >> 6;
    if (lane == 0) sb[w] = s;
    __syncthreads();
    if (threadIdx.x == 0) out[0] = (sb[0] + sb[1] + sb[2] + sb[3]) * (1.0f / (float)BNE);
}

extern "C" void kernel_launch(void* const* d_in, const int* in_sizes, int n_in,
                              void* d_out, int out_size, void* d_ws, size_t ws_size,
                              hipStream_t stream) {
    const float* x     = (const float*)d_in[0];
    const float* p     = (const float*)d_in[1];
    const float* wq    = (const float*)d_in[2];
    const float* bq    = (const float*)d_in[3];
    const float* wk    = (const float*)d_in[4];
    const float* bk    = (const float*)d_in[5];
    const float* wv    = (const float*)d_in[6];
    const float* bv    = (const float*)d_in[7];
    const float* wo    = (const float*)d_in[8];
    const float* bo    = (const float*)d_in[9];
    const float* w1    = (const float*)d_in[10];
    const float* b1    = (const float*)d_in[11];
    const float* w2    = (const float*)d_in[12];
    const float* b2    = (const float*)d_in[13];
    const float* g1    = (const float*)d_in[14];
    const float* beta1 = (const float*)d_in[15];
    const float* g2    = (const float*)d_in[16];
    const float* beta2 = (const float*)d_in[17];

    char* ws = (char*)d_ws;
    size_t off = 0;
    auto alloc = [&](size_t bytes) { void* pp = ws + off; off += (bytes + 255) & ~(size_t)255; return pp; };
    unsigned short* wqkvT = (unsigned short*)alloc((size_t)3 * Ecst * Ecst * 2);
    unsigned short* woT  = (unsigned short*)alloc((size_t)Ecst * Ecst * 2);
    unsigned short* w1T  = (unsigned short*)alloc((size_t)4 * Ecst * Ecst * 2);
    unsigned short* w2T  = (unsigned short*)alloc((size_t)4 * Ecst * Ecst * 2);
    float* bqkv          = (float*)alloc(3 * Ecst * 4);
    unsigned short* xn   = (unsigned short*)alloc((size_t)Mrows * Ecst * 2);  // reused as h after LN2
    unsigned short* qkv  = (unsigned short*)alloc((size_t)Mrows * 3 * Ecst * 2);
    unsigned short* aob  = (unsigned short*)alloc((size_t)Mrows * Ecst * 2);
    unsigned short* ff1  = (unsigned short*)alloc((size_t)Mrows * 4 * Ecst * 2);
    float* partials      = (float*)alloc(2048 * 4);

    float* x1 = (float*)d_out;                    // [0, BNE): x1 then x2 (copy 0)
    float* out2 = (float*)d_out + BNE;            // x2 (copy 1)
    float* lossp = (float*)d_out + 2 * (size_t)BNE;

    dim3 tb(32, 8);
    transpose_cast<<<dim3(32, 32),  tb, 0, stream>>>(wq, wqkvT, Ecst, Ecst);
    transpose_cast<<<dim3(32, 32),  tb, 0, stream>>>(wk, wqkvT + (size_t)Ecst * Ecst, Ecst, Ecst);
    transpose_cast<<<dim3(32, 32),  tb, 0, stream>>>(wv, wqkvT + (size_t)2 * Ecst * Ecst, Ecst, Ecst);
    transpose_cast<<<dim3(32, 32),  tb, 0, stream>>>(wo, woT, Ecst, Ecst);
    transpose_cast<<<dim3(128, 32), tb, 0, stream>>>(w1, w1T, Ecst, 4 * Ecst);
    transpose_cast<<<dim3(32, 128), tb, 0, stream>>>(w2, w2T, 4 * Ecst, Ecst);
    concat3<<<4, 256, 0, stream>>>(bq, bk, bv, bqkv);

    ln_kernel<<<Mrows, 256, 0, stream>>>(x, g1, beta1, xn);

    // fused QKV: M=16384, N=3072, K=1024  [gemm128w]
    gemm128w<0, 1024><<<64 * 24, 512, 0, stream>>>(xn, wqkvT, bqkv, 3 * Ecst, 24, qkv, nullptr, nullptr, nullptr);

    attn_mfma<<<Bb * Hh * (Nn_ / Cc_), 256, 0, stream>>>(qkv, aob);

    // WO: M=16384, N=1024, K=1024  [gemm4w PROBE: 256-thread VGPR budget test]
    gemm4w<1, 1024><<<64 * 8, 256, 0, stream>>>(aob, woT, bo, Ecst, 8, nullptr, x1, x, nullptr);

    ln_kernel<<<Mrows, 256, 0, stream>>>(x1, g2, beta2, xn);

    // FFN1: M=16384, N=4096, K=1024  [gemm128w]
    gemm128w<2, 1024><<<64 * 32, 512, 0, stream>>>(xn, w1T, b1, 4 * Ecst, 32, ff1, nullptr, nullptr, nullptr);

    // FFN2: M=16384, N=1024, K=4096  [gemm128w]
    gemm128w<3, 4096><<<64 * 8, 512, 0, stream>>>(ff1, w2T, b2, Ecst, 8, nullptr, x1, x1, out2);

    loss_partial<<<2048, 256, 0, stream>>>((const float*)d_out, p, partials);
    loss_final<<<1, 256, 0, stream>>>(partials, lossp);
}

// Round 8
// 977.764 us; speedup vs baseline: 1.7333x; 1.0010x over previous
//
#include <hip/hip_runtime.h>
#include <hip/hip_bf16.h>

// Problem constants
#define Ecst 1024
#define Hh 16
#define Dd 64
#define Cc_ 64
#define Bb 4
#define Nn_ 4096
#define Mrows (Bb*Nn_)          // 16384 token rows
#define BNE (Bb*Nn_*Ecst)       // 16,777,216

typedef __attribute__((ext_vector_type(4))) float f32x4;
typedef __attribute__((ext_vector_type(8))) short short8;
typedef __attribute__((ext_vector_type(4))) unsigned short ushort4v;

__device__ __forceinline__ float bf2f(unsigned short u) {
    union { float f; unsigned int i; } x; x.i = ((unsigned int)u) << 16; return x.f;
}
__device__ __forceinline__ unsigned short f2bf(float f) {
    __hip_bfloat16 h = __float2bfloat16(f);
    return *reinterpret_cast<unsigned short*>(&h);
}
// async global->LDS, 16B per lane. lds ptr must be wave-uniform base (+lane*16 implicit).
__device__ __forceinline__ void glds16(const unsigned short* g, unsigned short* l) {
    __builtin_amdgcn_global_load_lds(
        (const __attribute__((address_space(1))) unsigned int*)g,
        (__attribute__((address_space(3))) unsigned int*)l, 16, 0, 0);
}

// ---------------- weight transpose + cast: in [R][C] f32 -> out [C][R] bf16 ----
__global__ __launch_bounds__(256) void transpose_cast(const float* __restrict__ in,
                                                      unsigned short* __restrict__ out,
                                                      int R, int Cc) {
    __shared__ float tile[32][33];
    int c0 = blockIdx.x * 32, r0 = blockIdx.y * 32;
    int tx = threadIdx.x, ty = threadIdx.y;      // block (32,8)
#pragma unroll
    for (int i = 0; i < 4; ++i)
        tile[ty + i*8][tx] = in[(size_t)(r0 + ty + i*8) * Cc + c0 + tx];
    __syncthreads();
#pragma unroll
    for (int i = 0; i < 4; ++i)
        out[(size_t)(c0 + ty + i*8) * R + r0 + tx] = f2bf(tile[tx][ty + i*8]);
}

__global__ __launch_bounds__(256) void concat3(const float* __restrict__ a,
                                               const float* __restrict__ b,
                                               const float* __restrict__ c,
                                               float* __restrict__ o) {
    int i = blockIdx.x * 256 + threadIdx.x;
    if (i < 1024) { o[i] = a[i]; o[1024 + i] = b[i]; o[2048 + i] = c[i]; }
}

// ---------------- LayerNorm: x f32 [rows][1024] -> out bf16 -------------------
__global__ __launch_bounds__(256) void ln_kernel(const float* __restrict__ x,
                                                 const float* __restrict__ g,
                                                 const float* __restrict__ be,
                                                 unsigned short* __restrict__ out) {
    int row = blockIdx.x, tid = threadIdx.x;
    const float4 xv = *(const float4*)(x + (size_t)row * Ecst + tid * 4);
    float s = xv.x + xv.y + xv.z + xv.w;
    float q = xv.x*xv.x + xv.y*xv.y + xv.z*xv.z + xv.w*xv.w;
#pragma unroll
    for (int off = 32; off; off >>= 1) { s += __shfl_xor(s, off); q += __shfl_xor(q, off); }
    __shared__ float sb[8];
    int lane = tid & 63, w = tid >> 6;
    if (lane == 0) { sb[w] = s; sb[4 + w] = q; }
    __syncthreads();
    s = sb[0] + sb[1] + sb[2] + sb[3];
    q = sb[4] + sb[5] + sb[6] + sb[7];
    float mean = s * (1.0f / Ecst);
    float var  = q * (1.0f / Ecst) - mean * mean;
    float rs = rsqrtf(var + 1e-5f);
    ushort4v o;
    const float* xp = (const float*)&xv;
#pragma unroll
    for (int u = 0; u < 4; ++u) {
        float val = (xp[u] - mean) * rs * g[tid*4+u] + be[tid*4+u];
        o[u] = f2bf(val);
    }
    *(ushort4v*)(out + (size_t)row * Ecst + tid * 4) = o;
}

// Common epilogue
#define EPILOGUE(grow_expr, gcol_expr, MREP, NREP) \
    { \
        _Pragma("unroll") for (int mi = 0; mi < MREP; ++mi) { \
        _Pragma("unroll") for (int ni = 0; ni < NREP; ++ni) { \
            int gcol = gcol_expr; \
            float bia = bias[gcol]; \
            _Pragma("unroll") for (int j = 0; j < 4; ++j) { \
                int grow = grow_expr; \
                size_t idx = (size_t)grow * Nc + gcol; \
                float val = acc[mi][ni][j] + bia; \
                if (EPI == 0) { \
                    Ob[idx] = f2bf(val); \
                } else if (EPI == 1) { \
                    Of[idx] = resid[idx] + val; \
                } else if (EPI == 2) { \
                    Ob[idx] = f2bf(0.5f * val * (1.0f + erff(val * 0.70710678118654752f))); \
                } else { \
                    float v2 = resid[idx] + val; \
                    Of[idx] = v2; Of2[idx] = v2; \
                } \
            } \
        } } \
    }

// ---------------- bf16 MFMA GEMM: 128x128 tile, 4 waves, BK=32, ring-3 --------
// m97's occupancy regime (48 KB LDS -> 3 blocks/CU = 12 waves/CU of cross-block
// TLP, the proven latency-hider, m114) PLUS counted vmcnt(4) (no drain-to-0 in
// steady state) and the validated both-sides seg-XOR swizzle (0 bank conflicts,
// round-3 PMC). acc[4][4] = 64 VGPRs -> fits even the 128-VGPR budget observed
// on this toolchain (rounds 3-6: big-acc variants always spilled).
// Round-7 lesson: 72-96 KB LDS designs -> 1 block/CU -> staging latency exposed
// (FFN2: MfmaUtil 18.5%, 439 TF). This kernel trades LDS for TLP.
template<int EPI, int K>
__global__ __launch_bounds__(256)
void gemm128(const unsigned short* __restrict__ A,
             const unsigned short* __restrict__ Bt,
             const float* __restrict__ bias,
             int Nc, int nbn,
             unsigned short* __restrict__ Ob,
             float* __restrict__ Of,
             const float* __restrict__ resid,
             float* __restrict__ Of2) {
    __shared__ unsigned short AsL[3][4096];   // 3 x 8 KB (128 rows x 32)
    __shared__ unsigned short BsL[3][4096];   // 3 x 8 KB
    constexpr int NT = K / 32;
    const int tid = threadIdx.x;
    const int lane = tid & 63, wid = tid >> 6;    // 4 waves
    const int wm = wid >> 1, wn = wid & 1;        // wave tile: 64 x 64
    const int l = lane & 15, g = lane >> 4;
    const int nwg = gridDim.x, cpx = nwg >> 3;
    const int orig = blockIdx.x;
    const int wg = (orig & 7) * cpx + (orig >> 3);
    const int tm = (wg / nbn) * 128, tn = (wg % nbn) * 128;
    // A and B are each 128 rows x 4 16B-units = 512 units; 256 threads -> 2 sweeps
    const int u0 = tid, u1 = 256 + tid;
    const int r0 = u0 >> 2, r1 = u1 >> 2;
    const int sg0 = (u0 & 3) ^ ((r0 >> 1) & 3);
    const int sg1 = (u1 & 3) ^ ((r1 >> 1) & 3);
    const size_t aO0 = (size_t)(tm + r0) * K + sg0 * 8;
    const size_t aO1 = (size_t)(tm + r1) * K + sg1 * 8;
    const size_t bO0 = (size_t)(tn + r0) * K + sg0 * 8;
    const size_t bO1 = (size_t)(tn + r1) * K + sg1 * 8;
    const int wls0 = wid * 512;          // LDS elem base sweep 0 (wave-uniform)
    const int wls1 = 2048 + wid * 512;   // sweep 1
    auto stage = [&](int kt, unsigned short* SA, unsigned short* SB) {
        const unsigned short* gA = A + (size_t)kt * 32;
        const unsigned short* gB = Bt + (size_t)kt * 32;
        glds16(gA + aO0, SA + wls0);
        glds16(gB + bO0, SB + wls0);
        glds16(gA + aO1, SA + wls1);
        glds16(gB + bO1, SB + wls1);
    };
    const int seg = (g ^ ((l >> 1) & 3)) * 8;
    int frA[4], frB[4];
#pragma unroll
    for (int mi = 0; mi < 4; ++mi) frA[mi] = (wm * 64 + mi * 16 + l) * 32 + seg;
#pragma unroll
    for (int ni = 0; ni < 4; ++ni) frB[ni] = (wn * 64 + ni * 16 + l) * 32 + seg;

    f32x4 acc[4][4] = {};
    stage(0, AsL[0], BsL[0]);
    stage(1, AsL[1], BsL[1]);
    asm volatile("s_waitcnt vmcnt(4)" ::: "memory");   // tile 0 landed, tile 1 in flight
    __builtin_amdgcn_s_barrier();
    __builtin_amdgcn_sched_barrier(0);

#define TILEBODY(RA, RB, SA, SB) \
    { \
        if (t + 2 < NT) stage(t + 2, SA, SB); \
        short8 af[4], bfr[4]; \
        _Pragma("unroll") for (int mi = 0; mi < 4; ++mi) af[mi] = *(const short8*)(RA + frA[mi]); \
        _Pragma("unroll") for (int ni = 0; ni < 4; ++ni) bfr[ni] = *(const short8*)(RB + frB[ni]); \
        __builtin_amdgcn_s_setprio(1); \
        _Pragma("unroll") for (int mi = 0; mi < 4; ++mi) \
        _Pragma("unroll") for (int ni = 0; ni < 4; ++ni) \
            acc[mi][ni] = __builtin_amdgcn_mfma_f32_16x16x32_bf16(af[mi], bfr[ni], acc[mi][ni], 0, 0, 0); \
        __builtin_amdgcn_s_setprio(0); \
        if (t + 2 < NT) { asm volatile("s_waitcnt vmcnt(4)" ::: "memory"); } \
        else            { asm volatile("s_waitcnt vmcnt(0)" ::: "memory"); } \
        __builtin_amdgcn_s_barrier(); \
        __builtin_amdgcn_sched_barrier(0); \
    }

    int m3 = 0;
    for (int t = 0; t < NT; ++t) {
        if (m3 == 0)      TILEBODY(AsL[0], BsL[0], AsL[2], BsL[2])
        else if (m3 == 1) TILEBODY(AsL[1], BsL[1], AsL[0], BsL[0])
        else              TILEBODY(AsL[2], BsL[2], AsL[1], BsL[1])
        if (++m3 == 3) m3 = 0;
    }
#undef TILEBODY

    EPILOGUE(tm + wm * 64 + mi * 16 + g * 4 + j, tn + wn * 64 + ni * 16 + l, 4, 4)
}

// ---------------- chunked sliding-window attention (MFMA) ---------------------
#define QS_OFF(r,d0) ((r)*64  + ((((d0)>>3) ^ ((r)&7))  << 3))
#define KS_OFF(j,d0) ((j)*64  + ((((d0)>>3) ^ ((j)&7))  << 3))
#define VT_OFF(d,j0) ((d)*128 + ((((j0)>>3) ^ ((d)&15)) << 3))
#define PS_OFF(r,c0) ((r)*128 + ((((c0)>>3) ^ ((r)&15)) << 3))
__global__ __launch_bounds__(256) void attn_mfma(const unsigned short* __restrict__ qkv,
                                                 unsigned short* __restrict__ ao) {
    __shared__ unsigned short qs[64 * 64];
    __shared__ unsigned short ks[128 * 64];
    __shared__ unsigned short vT[64 * 128];
    __shared__ unsigned short ps[64 * 128];
    int bx = blockIdx.x;
    int c = bx & 63, h = (bx >> 6) & 15, b = bx >> 10;
    int tid = threadIdx.x, lane = tid & 63, w = tid >> 6;
    const int QKV = 3 * Ecst;
    size_t baseq = ((size_t)b * Nn_ + c * 64) * QKV + h * 64;
    size_t baseo = ((size_t)b * Nn_ + c * 64) * Ecst + h * 64;
#pragma unroll
    for (int i = 0; i < 2; ++i) {
        int cc = tid + i * 256;
        int row = cc >> 3, d0 = (cc & 7) * 8;
        short8 vq = *(const short8*)(qkv + baseq + (size_t)row * QKV + d0);
        *(short8*)(qs + QS_OFF(row, d0)) = vq;
    }
#pragma unroll
    for (int i = 0; i < 4; ++i) {
        int cc = tid + i * 256;
        int j = cc >> 3, d0 = (cc & 7) * 8;
        short8 vk = {}; short8 vv = {};
        if (c > 0 || j >= 64) {
            int srcRow = (j < 64) ? (c - 1) * 64 + j : c * 64 + (j - 64);
            size_t sb = ((size_t)b * Nn_ + srcRow) * QKV + h * 64 + d0;
            vk = *(const short8*)(qkv + sb + 1024);
            vv = *(const short8*)(qkv + sb + 2048);
        }
        *(short8*)(ks + KS_OFF(j, d0)) = vk;
#pragma unroll
        for (int u = 0; u < 8; ++u)
            vT[VT_OFF(d0 + u, j & ~7) + (j & 7)] = ((unsigned short*)&vv)[u];
    }
    __syncthreads();
    const int rA = w * 16 + (lane & 15);
    const int ksel = (lane >> 4) * 8;
    f32x4 s[8] = {};
#pragma unroll
    for (int kk = 0; kk < 2; ++kk) {
        short8 aq = *(const short8*)(qs + QS_OFF(rA, kk * 32 + ksel));
#pragma unroll
        for (int ni = 0; ni < 8; ++ni) {
            int j = ni * 16 + (lane & 15);
            short8 bk = *(const short8*)(ks + KS_OFF(j, kk * 32 + ksel));
            s[ni] = __builtin_amdgcn_mfma_f32_16x16x32_bf16(aq, bk, s[ni], 0, 0, 0);
        }
    }
    float inv[4];
    const int rq = (lane >> 4) * 4;
#pragma unroll
    for (int jr = 0; jr < 4; ++jr) {
        int i = w * 16 + rq + jr;
        float vals[8]; float mx = -1e30f;
#pragma unroll
        for (int ni = 0; ni < 8; ++ni) {
            int colw = ni * 16 + (lane & 15);
            bool valid = (colw < 64) || (colw - 64 <= i);
            float vv = valid ? s[ni][jr] * 0.125f : -1e30f;
            vals[ni] = vv;
            mx = fmaxf(mx, vv);
        }
#pragma unroll
        for (int off = 8; off; off >>= 1) mx = fmaxf(mx, __shfl_xor(mx, off));
        float sum = 0.f;
#pragma unroll
        for (int ni = 0; ni < 8; ++ni) {
            float e = (vals[ni] > -1e29f) ? __expf(vals[ni] - mx) : 0.f;
            vals[ni] = e; sum += e;
        }
#pragma unroll
        for (int off = 8; off; off >>= 1) sum += __shfl_xor(sum, off);
        inv[jr] = 1.0f / sum;
        int r = w * 16 + rq + jr;
#pragma unroll
        for (int ni = 0; ni < 8; ++ni) {
            int colw = ni * 16 + (lane & 15);
            ps[PS_OFF(r, colw & ~7) + (colw & 7)] = f2bf(vals[ni]);
        }
    }
    __syncthreads();
    f32x4 o[4] = {};
#pragma unroll
    for (int kk = 0; kk < 4; ++kk) {
        short8 ap = *(const short8*)(ps + PS_OFF(rA, kk * 32 + ksel));
#pragma unroll
        for (int ni = 0; ni < 4; ++ni) {
            int d = ni * 16 + (lane & 15);
            short8 bv = *(const short8*)(vT + VT_OFF(d, kk * 32 + ksel));
            o[ni] = __builtin_amdgcn_mfma_f32_16x16x32_bf16(ap, bv, o[ni], 0, 0, 0);
        }
    }
#pragma unroll
    for (int ni = 0; ni < 4; ++ni) {
#pragma unroll
        for (int jr = 0; jr < 4; ++jr) {
            int row = w * 16 + rq + jr;
            int d = ni * 16 + (lane & 15);
            ao[baseo + (size_t)row * Ecst + d] = f2bf(o[ni][jr] * inv[jr]);
        }
    }
}

// ---------------- loss ---------------------------------------------------------
__global__ __launch_bounds__(256) void loss_partial(const float* __restrict__ x2,
                                                    const float* __restrict__ p,
                                                    float* __restrict__ partials) {
    float s = 0.f;
    for (size_t idx = (size_t)blockIdx.x * 256 + threadIdx.x; idx < BNE / 4; idx += (size_t)gridDim.x * 256) {
        float4 a = *(const float4*)(x2 + idx * 4);
        float4 b = *(const float4*)(p + idx * 4);
        float dx = a.x - b.x, dy = a.y - b.y, dz = a.z - b.z, dw = a.w - b.w;
        s += dx*dx + dy*dy + dz*dz + dw*dw;
    }
#pragma unroll
    for (int off = 32; off; off >>= 1) s += __shfl_xor(s, off);
    __shared__ float sb[4];
    int lane = threadIdx.x & 63, w = threadIdx.x >> 6;
    if (lane == 0) sb[w] = s;
    __syncthreads();
    if (threadIdx.x == 0) partials[blockIdx.x] = sb[0] + sb[1] + sb[2] + sb[3];
}

__global__ __launch_bounds__(256) void loss_final(const float* __restrict__ partials,
                                                  float* __restrict__ out) {
    float s = 0.f;
    for (int i = threadIdx.x; i < 2048; i += 256) s += partials[i];
#pragma unroll
    for (int off = 32; off; off >>= 1) s += __shfl_xor(s, off);
    __shared__ float sb[4];
    int lane = threadIdx.x & 63, w = threadIdx.x >> 6;
    if (lane == 0) sb[w] = s;
    __syncthreads();
    if (threadIdx.x == 0) out[0] = (sb[0] + sb[1] + sb[2] + sb[3]) * (1.0f / (float)BNE);
}

extern "C" void kernel_launch(void* const* d_in, const int* in_sizes, int n_in,
                              void* d_out, int out_size, void* d_ws, size_t ws_size,
                              hipStream_t stream) {
    const float* x     = (const float*)d_in[0];
    const float* p     = (const float*)d_in[1];
    const float* wq    = (const float*)d_in[2];
    const float* bq    = (const float*)d_in[3];
    const float* wk    = (const float*)d_in[4];
    const float* bk    = (const float*)d_in[5];
    const float* wv    = (const float*)d_in[6];
    const float* bv    = (const float*)d_in[7];
    const float* wo    = (const float*)d_in[8];
    const float* bo    = (const float*)d_in[9];
    const float* w1    = (const float*)d_in[10];
    const float* b1    = (const float*)d_in[11];
    const float* w2    = (const float*)d_in[12];
    const float* b2    = (const float*)d_in[13];
    const float* g1    = (const float*)d_in[14];
    const float* beta1 = (const float*)d_in[15];
    const float* g2    = (const float*)d_in[16];
    const float* beta2 = (const float*)d_in[17];

    char* ws = (char*)d_ws;
    size_t off = 0;
    auto alloc = [&](size_t bytes) { void* pp = ws + off; off += (bytes + 255) & ~(size_t)255; return pp; };
    unsigned short* wqkvT = (unsigned short*)alloc((size_t)3 * Ecst * Ecst * 2);
    unsigned short* woT  = (unsigned short*)alloc((size_t)Ecst * Ecst * 2);
    unsigned short* w1T  = (unsigned short*)alloc((size_t)4 * Ecst * Ecst * 2);
    unsigned short* w2T  = (unsigned short*)alloc((size_t)4 * Ecst * Ecst * 2);
    float* bqkv          = (float*)alloc(3 * Ecst * 4);
    unsigned short* xn   = (unsigned short*)alloc((size_t)Mrows * Ecst * 2);  // reused as h after LN2
    unsigned short* qkv  = (unsigned short*)alloc((size_t)Mrows * 3 * Ecst * 2);
    unsigned short* aob  = (unsigned short*)alloc((size_t)Mrows * Ecst * 2);
    unsigned short* ff1  = (unsigned short*)alloc((size_t)Mrows * 4 * Ecst * 2);
    float* partials      = (float*)alloc(2048 * 4);

    float* x1 = (float*)d_out;                    // [0, BNE): x1 then x2 (copy 0)
    float* out2 = (float*)d_out + BNE;            // x2 (copy 1)
    float* lossp = (float*)d_out + 2 * (size_t)BNE;

    dim3 tb(32, 8);
    transpose_cast<<<dim3(32, 32),  tb, 0, stream>>>(wq, wqkvT, Ecst, Ecst);
    transpose_cast<<<dim3(32, 32),  tb, 0, stream>>>(wk, wqkvT + (size_t)Ecst * Ecst, Ecst, Ecst);
    transpose_cast<<<dim3(32, 32),  tb, 0, stream>>>(wv, wqkvT + (size_t)2 * Ecst * Ecst, Ecst, Ecst);
    transpose_cast<<<dim3(32, 32),  tb, 0, stream>>>(wo, woT, Ecst, Ecst);
    transpose_cast<<<dim3(128, 32), tb, 0, stream>>>(w1, w1T, Ecst, 4 * Ecst);
    transpose_cast<<<dim3(32, 128), tb, 0, stream>>>(w2, w2T, 4 * Ecst, Ecst);
    concat3<<<4, 256, 0, stream>>>(bq, bk, bv, bqkv);

    ln_kernel<<<Mrows, 256, 0, stream>>>(x, g1, beta1, xn);

    // fused QKV: M=16384, N=3072, K=1024
    gemm128<0, 1024><<<128 * 24, 256, 0, stream>>>(xn, wqkvT, bqkv, 3 * Ecst, 24, qkv, nullptr, nullptr, nullptr);

    attn_mfma<<<Bb * Hh * (Nn_ / Cc_), 256, 0, stream>>>(qkv, aob);

    // WO: M=16384, N=1024, K=1024
    gemm128<1, 1024><<<128 * 8, 256, 0, stream>>>(aob, woT, bo, Ecst, 8, nullptr, x1, x, nullptr);

    ln_kernel<<<Mrows, 256, 0, stream>>>(x1, g2, beta2, xn);

    // FFN1: M=16384, N=4096, K=1024
    gemm128<2, 1024><<<128 * 32, 256, 0, stream>>>(xn, w1T, b1, 4 * Ecst, 32, ff1, nullptr, nullptr, nullptr);

    // FFN2: M=16384, N=1024, K=4096
    gemm128<3, 4096><<<128 * 8, 256, 0, stream>>>(ff1, w2T, b2, Ecst, 8, nullptr, x1, x1, out2);

    loss_partial<<<2048, 256, 0, stream>>>((const float*)d_out, p, partials);
    loss_final<<<1, 256, 0, stream>>>(partials, lossp);
}